// Round 1
// baseline (1042.654 us; speedup 1.0000x reference)
//
#include <hip/hip_runtime.h>
#include <math.h>

#define N_NODES 100000
#define N_EDGES 3200000
#define D_IN    128
#define H_DIM   32
#define OUT_DIM 16
#define W2      17   // packed [Wm | Wv] width

// ---------------- degree / norm ----------------

__global__ void k_deg_init(float* deg) {
    int i = blockIdx.x * blockDim.x + threadIdx.x;
    if (i < N_NODES) deg[i] = 1.0f;          // self-loop
}

__global__ void k_deg_count(const int* __restrict__ dst, float* deg) {
    int e = blockIdx.x * blockDim.x + threadIdx.x;
    if (e < N_EDGES) atomicAdd(&deg[dst[e]], 1.0f);
}

__global__ void k_dinv(float* deg) {
    int i = blockIdx.x * blockDim.x + threadIdx.x;
    if (i < N_NODES) deg[i] = rsqrtf(deg[i]);   // deg>0 always (self-loop)
}

// ---------------- layer 1: h0 = x @ W1 ----------------
// block = 256 threads = 8 rows x 32 cols; W1 (128x32) staged in LDS.

__global__ __launch_bounds__(256) void k_gemm1(const float* __restrict__ x,
                                               const float* __restrict__ W1,
                                               float* __restrict__ h0) {
    __shared__ float sW[D_IN * H_DIM];   // 16 KB
    int tid = threadIdx.x;
    for (int k = tid; k < D_IN * H_DIM; k += 256) sW[k] = W1[k];
    __syncthreads();

    int row = blockIdx.x * 8 + (tid >> 5);
    int j   = tid & 31;
    if (row >= N_NODES) return;

    const float* xr = x + (size_t)row * D_IN;
    float acc = 0.f;
#pragma unroll
    for (int k = 0; k < D_IN; k += 4) {
        float4 xv = *(const float4*)(xr + k);
        acc += xv.x * sW[(k + 0) * H_DIM + j];
        acc += xv.y * sW[(k + 1) * H_DIM + j];
        acc += xv.z * sW[(k + 2) * H_DIM + j];
        acc += xv.w * sW[(k + 3) * H_DIM + j];
    }
    h0[(size_t)row * H_DIM + j] = acc;
}

// ---------------- edge scatter, layer 1 ----------------
// one thread per (edge, col): agg[d*32+c] += dinv[s]*dinv[d]*h0[s*32+c]

__global__ __launch_bounds__(256) void k_scatter1(const int* __restrict__ src,
                                                  const int* __restrict__ dst,
                                                  const float* __restrict__ dinv,
                                                  const float* __restrict__ h0,
                                                  float* agg) {
    long long t = (long long)blockIdx.x * blockDim.x + threadIdx.x;
    int e = (int)(t >> 5);
    int c = (int)(t & 31);
    if (e >= N_EDGES) return;
    int s = src[e], d = dst[e];
    float w = dinv[s] * dinv[d];
    atomicAdd(&agg[(size_t)d * H_DIM + c], w * h0[(size_t)s * H_DIM + c]);
}

// self-loop + bias + relu, in place -> h
__global__ __launch_bounds__(256) void k_finalize1(const float* __restrict__ dinv,
                                                   const float* __restrict__ h0,
                                                   const float* __restrict__ b1,
                                                   float* agg) {
    int t = blockIdx.x * blockDim.x + threadIdx.x;
    int i = t >> 5;
    int c = t & 31;
    if (i >= N_NODES) return;
    float di = dinv[i];
    float v = agg[(size_t)i * H_DIM + c] + di * di * h0[(size_t)i * H_DIM + c] + b1[c];
    agg[(size_t)i * H_DIM + c] = fmaxf(v, 0.f);
}

// ---------------- layer 2 projection: hmv[i,0:17] = h[i,:] @ [Wm|Wv] ----------------

__global__ __launch_bounds__(256) void k_gemm2(const float* __restrict__ h,
                                               const float* __restrict__ Wm,
                                               const float* __restrict__ Wv,
                                               float* __restrict__ hmv) {
    __shared__ float sW[H_DIM * W2];   // 32 x 17
    int tid = threadIdx.x;
    for (int idx = tid; idx < H_DIM * W2; idx += 256) {
        int k = idx / W2, c = idx % W2;
        sW[idx] = (c < OUT_DIM) ? Wm[k * OUT_DIM + c] : Wv[k];
    }
    __syncthreads();

    int i = blockIdx.x * blockDim.x + tid;
    if (i >= N_NODES) return;

    float hr[H_DIM];
    const float4* hp = (const float4*)(h + (size_t)i * H_DIM);
#pragma unroll
    for (int k4 = 0; k4 < H_DIM / 4; ++k4) {
        float4 v = hp[k4];
        hr[k4 * 4 + 0] = v.x; hr[k4 * 4 + 1] = v.y;
        hr[k4 * 4 + 2] = v.z; hr[k4 * 4 + 3] = v.w;
    }
    float acc[W2];
#pragma unroll
    for (int c = 0; c < W2; ++c) acc[c] = 0.f;
#pragma unroll
    for (int k = 0; k < H_DIM; ++k) {
        float hv = hr[k];
#pragma unroll
        for (int c = 0; c < W2; ++c) acc[c] += hv * sW[k * W2 + c];
    }
    float* o = hmv + (size_t)i * W2;
#pragma unroll
    for (int c = 0; c < W2; ++c) o[c] = acc[c];
}

// ---------------- edge scatter, layer 2 ----------------

__global__ __launch_bounds__(256) void k_scatter2(const int* __restrict__ src,
                                                  const int* __restrict__ dst,
                                                  const float* __restrict__ dinv,
                                                  const float* __restrict__ hmv,
                                                  float* agg2) {
    long long t = (long long)blockIdx.x * blockDim.x + threadIdx.x;
    int e = (int)(t / W2);
    int c = (int)(t % W2);
    if (e >= N_EDGES) return;
    int s = src[e], d = dst[e];
    float w = dinv[s] * dinv[d];
    atomicAdd(&agg2[(size_t)d * W2 + c], w * hmv[(size_t)s * W2 + c]);
}

// self-loop + bias + row-normalize(mean) + softplus(var)
__global__ __launch_bounds__(256) void k_finalize2(const float* __restrict__ dinv,
                                                   const float* __restrict__ hmv,
                                                   const float* __restrict__ bm,
                                                   const float* __restrict__ bv,
                                                   const float* __restrict__ agg2,
                                                   float* __restrict__ out) {
    int i = blockIdx.x * blockDim.x + threadIdx.x;
    if (i >= N_NODES) return;
    float di  = dinv[i];
    float di2 = di * di;

    float m[W2];
    float ss = 0.f;
#pragma unroll
    for (int c = 0; c < W2; ++c) {
        float b = (c < OUT_DIM) ? bm[c] : bv[0];
        float v = agg2[(size_t)i * W2 + c] + di2 * hmv[(size_t)i * W2 + c] + b;
        m[c] = v;
        if (c < OUT_DIM) ss += v * v;
    }
    float inv = rsqrtf(ss);
#pragma unroll
    for (int c = 0; c < OUT_DIM; ++c) out[(size_t)i * OUT_DIM + c] = m[c] * inv;

    float xv = m[OUT_DIM];
    float sp = fmaxf(xv, 0.f) + log1pf(expf(-fabsf(xv)));   // stable softplus
    out[(size_t)N_NODES * OUT_DIM + i] = sp + 1.0f;
}

// ---------------- launch ----------------

extern "C" void kernel_launch(void* const* d_in, const int* in_sizes, int n_in,
                              void* d_out, int out_size, void* d_ws, size_t ws_size,
                              hipStream_t stream) {
    const float* x  = (const float*)d_in[0];
    const int*   ei = (const int*)d_in[1];     // harness delivers integers as int32
    const float* W1 = (const float*)d_in[2];
    const float* b1 = (const float*)d_in[3];
    const float* Wm = (const float*)d_in[4];
    const float* bm = (const float*)d_in[5];
    const float* Wv = (const float*)d_in[6];
    const float* bv = (const float*)d_in[7];
    float* out = (float*)d_out;

    float* ws   = (float*)d_ws;
    float* dinv = ws;                          // N
    float* h0   = ws + N_NODES;                // 32N   (later reused as hmv, stride 17)
    float* agg1 = ws + (size_t)N_NODES * 33;   // 32N   (later h, then agg2)

    const int* src = ei;
    const int* dst = ei + N_EDGES;

    const int B = 256;
    int gN   = (N_NODES + B - 1) / B;
    int gE   = (N_EDGES + B - 1) / B;
    int gN32 = (N_NODES * H_DIM + B - 1) / B;
    long long e32 = (long long)N_EDGES * H_DIM;
    long long e17 = (long long)N_EDGES * W2;
    int gE32 = (int)((e32 + B - 1) / B);
    int gE17 = (int)((e17 + B - 1) / B);

    // degrees -> dinv
    k_deg_init<<<gN, B, 0, stream>>>(dinv);
    k_deg_count<<<gE, B, 0, stream>>>(dst, dinv);
    k_dinv<<<gN, B, 0, stream>>>(dinv);

    // layer 1
    k_gemm1<<<(N_NODES + 7) / 8, B, 0, stream>>>(x, W1, h0);
    hipMemsetAsync(agg1, 0, (size_t)N_NODES * H_DIM * sizeof(float), stream);
    k_scatter1<<<gE32, B, 0, stream>>>(src, dst, dinv, h0, agg1);
    k_finalize1<<<gN32, B, 0, stream>>>(dinv, h0, b1, agg1);   // agg1 now holds h

    // layer 2 projection into h0 space (stride 17)
    k_gemm2<<<gN, B, 0, stream>>>(agg1, Wm, Wv, h0);           // h0 now holds hmv

    // layer 2 scatter into agg1 space (h no longer needed)
    hipMemsetAsync(agg1, 0, (size_t)N_NODES * W2 * sizeof(float), stream);
    k_scatter2<<<gE17, B, 0, stream>>>(src, dst, dinv, h0, agg1);

    // finalize outputs
    k_finalize2<<<gN, B, 0, stream>>>(dinv, h0, bm, bv, agg1, out);
}

// Round 2
// 855.410 us; speedup vs baseline: 1.2189x; 1.2189x over previous
//
#include <hip/hip_runtime.h>
#include <math.h>

#define N_NODES 100000
#define N_EDGES 3200000
#define D_IN    128
#define H_DIM   32
#define OUT_DIM 16
#define W2      17   // packed [Wm | Wv] width
#define NBLK    ((N_NODES + 255) / 256)   // 391 scan blocks

// ---------------- degree histogram ----------------

__global__ __launch_bounds__(256) void k_hist(const int* __restrict__ dst, int* deg) {
    int e = blockIdx.x * 256 + threadIdx.x;
    if (e < N_EDGES) atomicAdd(&deg[dst[e]], 1);
}

// ---------------- 3-kernel exclusive scan over deg ----------------

__global__ __launch_bounds__(256) void k_scan_reduce(const int* __restrict__ deg,
                                                     int* __restrict__ psum) {
    __shared__ int s[256];
    int t = threadIdx.x;
    int i = blockIdx.x * 256 + t;
    s[t] = (i < N_NODES) ? deg[i] : 0;
    __syncthreads();
    for (int off = 128; off > 0; off >>= 1) {
        if (t < off) s[t] += s[t + off];
        __syncthreads();
    }
    if (t == 0) psum[blockIdx.x] = s[0];
}

__global__ __launch_bounds__(512) void k_scan_top(int* psum) {
    __shared__ int a[512], b[512];
    int t = threadIdx.x;
    a[t] = (t < NBLK) ? psum[t] : 0;
    __syncthreads();
    int* cur = a; int* nxt = b;
    for (int off = 1; off < 512; off <<= 1) {
        nxt[t] = cur[t] + ((t >= off) ? cur[t - off] : 0);
        __syncthreads();
        int* tmp = cur; cur = nxt; nxt = tmp;
    }
    if (t < NBLK) psum[t] = (t == 0) ? 0 : cur[t - 1];   // exclusive
}

// block-local exclusive scan + global offset; also emits cursor and dinv
__global__ __launch_bounds__(256) void k_scan_down(const int* __restrict__ deg,
                                                   const int* __restrict__ psum,
                                                   int* __restrict__ row_ptr,
                                                   int* __restrict__ cursor,
                                                   float* __restrict__ dinv) {
    __shared__ int a[256], b[256];
    int t = threadIdx.x;
    int i = blockIdx.x * 256 + t;
    int d = (i < N_NODES) ? deg[i] : 0;
    a[t] = d;
    __syncthreads();
    int* cur = a; int* nxt = b;
    for (int off = 1; off < 256; off <<= 1) {
        nxt[t] = cur[t] + ((t >= off) ? cur[t - off] : 0);
        __syncthreads();
        int* tmp = cur; cur = nxt; nxt = tmp;
    }
    int incl = cur[t];
    int base = psum[blockIdx.x];
    if (i < N_NODES) {
        int ex = base + incl - d;
        row_ptr[i] = ex;
        cursor[i]  = ex;
        dinv[i]    = rsqrtf((float)(d + 1));          // +1 self-loop
        if (i == N_NODES - 1) row_ptr[N_NODES] = base + incl;
    }
}

// ---------------- CSR fill (bucket edges by dst) ----------------

__global__ __launch_bounds__(256) void k_fill(const int* __restrict__ src,
                                              const int* __restrict__ dst,
                                              int* cursor, int* __restrict__ csr_src) {
    int e = blockIdx.x * 256 + threadIdx.x;
    if (e >= N_EDGES) return;
    int pos = atomicAdd(&cursor[dst[e]], 1);
    csr_src[pos] = src[e];
}

// ---------------- layer 1: h0 = x @ W1 ----------------

__global__ __launch_bounds__(256) void k_gemm1(const float* __restrict__ x,
                                               const float* __restrict__ W1,
                                               float* __restrict__ h0) {
    __shared__ float sW[D_IN * H_DIM];   // 16 KB
    int tid = threadIdx.x;
    for (int k = tid; k < D_IN * H_DIM; k += 256) sW[k] = W1[k];
    __syncthreads();

    int row = blockIdx.x * 8 + (tid >> 5);
    int j   = tid & 31;
    if (row >= N_NODES) return;

    const float* xr = x + (size_t)row * D_IN;
    float acc = 0.f;
#pragma unroll
    for (int k = 0; k < D_IN; k += 4) {
        float4 xv = *(const float4*)(xr + k);
        acc += xv.x * sW[(k + 0) * H_DIM + j];
        acc += xv.y * sW[(k + 1) * H_DIM + j];
        acc += xv.z * sW[(k + 2) * H_DIM + j];
        acc += xv.w * sW[(k + 3) * H_DIM + j];
    }
    h0[(size_t)row * H_DIM + j] = acc;
}

// ---------------- layer-1 aggregation: pull over neighbors ----------------
// thread = (node i, col c); h[i,c] = relu(dinv[i]*(dinv[i]*h0[i,c] + sum_s dinv[s]*h0[s,c]) + b1[c])

__global__ __launch_bounds__(256) void k_gather1(const int* __restrict__ row_ptr,
                                                 const int* __restrict__ csr_src,
                                                 const float* __restrict__ dinv,
                                                 const float* __restrict__ h0,
                                                 const float* __restrict__ b1,
                                                 float* __restrict__ h) {
    int t = blockIdx.x * 256 + threadIdx.x;
    int i = t >> 5, c = t & 31;
    if (i >= N_NODES) return;
    int start = row_ptr[i], end = row_ptr[i + 1];
    float di = dinv[i];
    float acc = di * h0[(size_t)i * H_DIM + c];      // self-loop term
    for (int j = start; j < end; ++j) {
        int s = csr_src[j];
        acc += dinv[s] * h0[(size_t)s * H_DIM + c];
    }
    float v = di * acc + b1[c];
    h[(size_t)i * H_DIM + c] = fmaxf(v, 0.f);
}

// ---------------- layer 2 projection: hmv[i,0:17] = h[i,:] @ [Wm|Wv] ----------------

__global__ __launch_bounds__(256) void k_gemm2(const float* __restrict__ h,
                                               const float* __restrict__ Wm,
                                               const float* __restrict__ Wv,
                                               float* __restrict__ hmv) {
    __shared__ float sW[H_DIM * W2];
    int tid = threadIdx.x;
    for (int idx = tid; idx < H_DIM * W2; idx += 256) {
        int k = idx / W2, c = idx % W2;
        sW[idx] = (c < OUT_DIM) ? Wm[k * OUT_DIM + c] : Wv[k];
    }
    __syncthreads();

    int i = blockIdx.x * 256 + tid;
    if (i >= N_NODES) return;

    float hr[H_DIM];
    const float4* hp = (const float4*)(h + (size_t)i * H_DIM);
#pragma unroll
    for (int k4 = 0; k4 < H_DIM / 4; ++k4) {
        float4 v = hp[k4];
        hr[k4 * 4 + 0] = v.x; hr[k4 * 4 + 1] = v.y;
        hr[k4 * 4 + 2] = v.z; hr[k4 * 4 + 3] = v.w;
    }
    float acc[W2];
#pragma unroll
    for (int c = 0; c < W2; ++c) acc[c] = 0.f;
#pragma unroll
    for (int k = 0; k < H_DIM; ++k) {
        float hv = hr[k];
#pragma unroll
        for (int c = 0; c < W2; ++c) acc[c] += hv * sW[k * W2 + c];
    }
    float* o = hmv + (size_t)i * W2;
#pragma unroll
    for (int c = 0; c < W2; ++c) o[c] = acc[c];
}

// ---------------- layer-2 aggregation (pull), bias fused ----------------

__global__ __launch_bounds__(256) void k_gather2(const int* __restrict__ row_ptr,
                                                 const int* __restrict__ csr_src,
                                                 const float* __restrict__ dinv,
                                                 const float* __restrict__ hmv,
                                                 const float* __restrict__ bm,
                                                 const float* __restrict__ bv,
                                                 float* __restrict__ mv) {
    long long t = (long long)blockIdx.x * 256 + threadIdx.x;
    int i = (int)(t / W2), c = (int)(t % W2);
    if (i >= N_NODES) return;
    int start = row_ptr[i], end = row_ptr[i + 1];
    float di = dinv[i];
    float acc = di * hmv[(size_t)i * W2 + c];        // self-loop term
    for (int j = start; j < end; ++j) {
        int s = csr_src[j];
        acc += dinv[s] * hmv[(size_t)s * W2 + c];
    }
    float b = (c < OUT_DIM) ? bm[c] : bv[0];
    mv[(size_t)i * W2 + c] = di * acc + b;
}

// ---------------- normalize(mean) + softplus(var) ----------------

__global__ __launch_bounds__(256) void k_finalize2(const float* __restrict__ mv,
                                                   float* __restrict__ out) {
    int i = blockIdx.x * 256 + threadIdx.x;
    if (i >= N_NODES) return;
    float m[OUT_DIM];
    float ss = 0.f;
#pragma unroll
    for (int c = 0; c < OUT_DIM; ++c) {
        float v = mv[(size_t)i * W2 + c];
        m[c] = v;
        ss += v * v;
    }
    float inv = rsqrtf(ss);
#pragma unroll
    for (int c = 0; c < OUT_DIM; ++c) out[(size_t)i * OUT_DIM + c] = m[c] * inv;

    float xv = mv[(size_t)i * W2 + OUT_DIM];
    float sp = fmaxf(xv, 0.f) + log1pf(expf(-fabsf(xv)));   // stable softplus
    out[(size_t)N_NODES * OUT_DIM + i] = sp + 1.0f;
}

// ---------------- launch ----------------

extern "C" void kernel_launch(void* const* d_in, const int* in_sizes, int n_in,
                              void* d_out, int out_size, void* d_ws, size_t ws_size,
                              hipStream_t stream) {
    const float* x  = (const float*)d_in[0];
    const int*   ei = (const int*)d_in[1];
    const float* W1 = (const float*)d_in[2];
    const float* b1 = (const float*)d_in[3];
    const float* Wm = (const float*)d_in[4];
    const float* bm = (const float*)d_in[5];
    const float* Wv = (const float*)d_in[6];
    const float* bv = (const float*)d_in[7];
    float* out = (float*)d_out;

    const int* src = ei;
    const int* dst = ei + N_EDGES;

    // workspace layout (all 4B elements)
    int*   wsi     = (int*)d_ws;
    int*   deg     = wsi;                       // N
    int*   psum    = deg + N_NODES;             // 512
    int*   row_ptr = psum + 512;                // N+1
    int*   cursor  = row_ptr + N_NODES + 1;     // N
    int*   csr_src = cursor + N_NODES;          // E
    float* dinv    = (float*)(csr_src + N_EDGES);        // N
    float* bufA    = dinv + N_NODES;            // 32N: h0, later hmv (17N)
    float* bufB    = bufA + (size_t)N_NODES * H_DIM;     // 32N: h, later mv (17N)

    const int B = 256;
    int gN  = (N_NODES + B - 1) / B;
    int gE  = (N_EDGES + B - 1) / B;
    int gN32 = (N_NODES * H_DIM + B - 1) / B;
    int gN17 = (int)(((long long)N_NODES * W2 + B - 1) / B);

    // --- CSR build ---
    hipMemsetAsync(deg, 0, N_NODES * sizeof(int), stream);
    k_hist<<<gE, B, 0, stream>>>(dst, deg);
    k_scan_reduce<<<NBLK, B, 0, stream>>>(deg, psum);
    k_scan_top<<<1, 512, 0, stream>>>(psum);
    k_scan_down<<<NBLK, B, 0, stream>>>(deg, psum, row_ptr, cursor, dinv);
    k_fill<<<gE, B, 0, stream>>>(src, dst, cursor, csr_src);

    // --- layer 1 ---
    k_gemm1<<<(N_NODES + 7) / 8, B, 0, stream>>>(x, W1, bufA);          // h0
    k_gather1<<<gN32, B, 0, stream>>>(row_ptr, csr_src, dinv, bufA, b1, bufB);  // h

    // --- layer 2 ---
    k_gemm2<<<gN, B, 0, stream>>>(bufB, Wm, Wv, bufA);                  // hmv
    k_gather2<<<gN17, B, 0, stream>>>(row_ptr, csr_src, dinv, bufA, bm, bv, bufB); // mv

    // --- outputs ---
    k_finalize2<<<gN, B, 0, stream>>>(bufB, out);
}

// Round 3
// 763.565 us; speedup vs baseline: 1.3655x; 1.1203x over previous
//
#include <hip/hip_runtime.h>
#include <math.h>

#define N_NODES   100000
#define N_EDGES   3200000
#define D_IN      128
#define H_DIM     32
#define OUT_DIM   16
#define MV_STRIDE 20   // padded [Wm | Wv] row stride (float4-aligned: 80 B)

// ---------------- adjacency build: atomic linked lists ----------------
// head[d] = most recent edge into d; next[e] = previous edge into same d.
// next write is COALESCED (indexed by e); only the int atomics touch head.

__global__ __launch_bounds__(256) void k_build(const int* __restrict__ dst,
                                               int* deg, int* head,
                                               int* __restrict__ next) {
    int e = blockIdx.x * 256 + threadIdx.x;
    if (e >= N_EDGES) return;
    int d = dst[e];
    atomicAdd(&deg[d], 1);
    next[e] = atomicExch(&head[d], e);
}

// deg (int, in-place) -> dinv = rsqrt(deg + 1)  (+1 self-loop)
__global__ __launch_bounds__(256) void k_dinv(float* degv) {
    int i = blockIdx.x * 256 + threadIdx.x;
    if (i < N_NODES) {
        int v = ((int*)degv)[i];
        degv[i] = rsqrtf((float)v + 1.0f);
    }
}

// ---------------- layer 1: hs = dinv[i] * (x @ W1) ----------------
// block = 256 threads = 8 rows x 32 cols; W1 (128x32) staged in LDS.

__global__ __launch_bounds__(256) void k_gemm1(const float* __restrict__ x,
                                               const float* __restrict__ W1,
                                               const float* __restrict__ dinv,
                                               float* __restrict__ hs) {
    __shared__ float sW[D_IN * H_DIM];   // 16 KB
    int tid = threadIdx.x;
    for (int k = tid; k < D_IN * H_DIM; k += 256) sW[k] = W1[k];
    __syncthreads();

    int row = blockIdx.x * 8 + (tid >> 5);
    int j   = tid & 31;
    if (row >= N_NODES) return;

    const float* xr = x + (size_t)row * D_IN;
    float acc = 0.f;
#pragma unroll
    for (int k = 0; k < D_IN; k += 4) {
        float4 xv = *(const float4*)(xr + k);
        acc += xv.x * sW[(k + 0) * H_DIM + j];
        acc += xv.y * sW[(k + 1) * H_DIM + j];
        acc += xv.z * sW[(k + 2) * H_DIM + j];
        acc += xv.w * sW[(k + 3) * H_DIM + j];
    }
    hs[(size_t)row * H_DIM + j] = acc * dinv[row];
}

// ---------------- layer-1 aggregation: chain walk, pull ----------------
// 8 lanes per node, each owns 4 cols (float4).
// h[i,:] = relu(dinv[i] * (hs[i,:] + sum_nb hs[s,:]) + b1)

__global__ __launch_bounds__(256) void k_gather1(const int* __restrict__ head,
                                                 const int* __restrict__ next,
                                                 const int* __restrict__ src,
                                                 const float* __restrict__ dinv,
                                                 const float* __restrict__ hs,
                                                 const float* __restrict__ b1,
                                                 float* __restrict__ h) {
    int t = blockIdx.x * 256 + threadIdx.x;
    int i = t >> 3, c = t & 7;
    if (i >= N_NODES) return;

    float4 acc = *(const float4*)(hs + (size_t)i * H_DIM + c * 4);  // self term
    int e = head[i];
    while (e >= 0) {
        int s = src[e];      // off-chain load
        e = next[e];         // the only loop-carried dependency
        float4 v = *(const float4*)(hs + (size_t)s * H_DIM + c * 4);
        acc.x += v.x; acc.y += v.y; acc.z += v.z; acc.w += v.w;
    }
    float di = dinv[i];
    float4 b = *(const float4*)(b1 + c * 4);
    float4 o;
    o.x = fmaxf(di * acc.x + b.x, 0.f);
    o.y = fmaxf(di * acc.y + b.y, 0.f);
    o.z = fmaxf(di * acc.z + b.z, 0.f);
    o.w = fmaxf(di * acc.w + b.w, 0.f);
    *(float4*)(h + (size_t)i * H_DIM + c * 4) = o;
}

// ---------------- layer 2 projection: hmv = dinv[i] * (h @ [Wm|Wv]), stride 20 ----------------

__global__ __launch_bounds__(256) void k_gemm2(const float* __restrict__ h,
                                               const float* __restrict__ Wm,
                                               const float* __restrict__ Wv,
                                               const float* __restrict__ dinv,
                                               float* __restrict__ hmv) {
    __shared__ float sW[H_DIM * (OUT_DIM + 1)];
    int tid = threadIdx.x;
    for (int idx = tid; idx < H_DIM * (OUT_DIM + 1); idx += 256) {
        int k = idx / (OUT_DIM + 1), c = idx % (OUT_DIM + 1);
        sW[idx] = (c < OUT_DIM) ? Wm[k * OUT_DIM + c] : Wv[k];
    }
    __syncthreads();

    int i = blockIdx.x * 256 + tid;
    if (i >= N_NODES) return;

    float hr[H_DIM];
    const float4* hp = (const float4*)(h + (size_t)i * H_DIM);
#pragma unroll
    for (int k4 = 0; k4 < H_DIM / 4; ++k4) {
        float4 v = hp[k4];
        hr[k4 * 4 + 0] = v.x; hr[k4 * 4 + 1] = v.y;
        hr[k4 * 4 + 2] = v.z; hr[k4 * 4 + 3] = v.w;
    }
    float acc[OUT_DIM + 1];
#pragma unroll
    for (int c = 0; c <= OUT_DIM; ++c) acc[c] = 0.f;
#pragma unroll
    for (int k = 0; k < H_DIM; ++k) {
        float hv = hr[k];
#pragma unroll
        for (int c = 0; c <= OUT_DIM; ++c) acc[c] += hv * sW[k * (OUT_DIM + 1) + c];
    }
    float di = dinv[i];
    float* o = hmv + (size_t)i * MV_STRIDE;
#pragma unroll
    for (int c = 0; c <= OUT_DIM; ++c) o[c] = acc[c] * di;
}

// ---------------- layer-2 aggregation: chain walk ----------------
// 8 lanes per node: lanes 0-3 float4 (cols 0-15), lane 4 float4 at col 16
// (cols 17-19 are stale-but-finite pad, discarded), lanes 5-7 exit.

__global__ __launch_bounds__(256) void k_gather2(const int* __restrict__ head,
                                                 const int* __restrict__ next,
                                                 const int* __restrict__ src,
                                                 const float* __restrict__ dinv,
                                                 const float* __restrict__ hmv,
                                                 const float* __restrict__ bm,
                                                 const float* __restrict__ bv,
                                                 float* __restrict__ mv) {
    int t = blockIdx.x * 256 + threadIdx.x;
    int i = t >> 3, c = t & 7;
    if (i >= N_NODES || c > 4) return;

    float4 acc = *(const float4*)(hmv + (size_t)i * MV_STRIDE + c * 4);  // self
    int e = head[i];
    while (e >= 0) {
        int s = src[e];
        e = next[e];
        float4 v = *(const float4*)(hmv + (size_t)s * MV_STRIDE + c * 4);
        acc.x += v.x; acc.y += v.y; acc.z += v.z; acc.w += v.w;
    }
    float di = dinv[i];
    float* o = mv + (size_t)i * MV_STRIDE + c * 4;
    if (c < 4) {
        float4 b = *(const float4*)(bm + c * 4);
        float4 r;
        r.x = di * acc.x + b.x;
        r.y = di * acc.y + b.y;
        r.z = di * acc.z + b.z;
        r.w = di * acc.w + b.w;
        *(float4*)o = r;
    } else {
        o[0] = di * acc.x + bv[0];   // col 16 (var)
    }
}

// ---------------- normalize(mean) + softplus(var) ----------------

__global__ __launch_bounds__(256) void k_finalize2(const float* __restrict__ mv,
                                                   float* __restrict__ out) {
    int i = blockIdx.x * 256 + threadIdx.x;
    if (i >= N_NODES) return;
    float m[OUT_DIM];
    float ss = 0.f;
#pragma unroll
    for (int c = 0; c < OUT_DIM; ++c) {
        float v = mv[(size_t)i * MV_STRIDE + c];
        m[c] = v;
        ss += v * v;
    }
    float inv = rsqrtf(ss);
#pragma unroll
    for (int c = 0; c < OUT_DIM; ++c) out[(size_t)i * OUT_DIM + c] = m[c] * inv;

    float xv = mv[(size_t)i * MV_STRIDE + OUT_DIM];
    float sp = fmaxf(xv, 0.f) + log1pf(expf(-fabsf(xv)));   // stable softplus
    out[(size_t)N_NODES * OUT_DIM + i] = sp + 1.0f;
}

// ---------------- launch ----------------

extern "C" void kernel_launch(void* const* d_in, const int* in_sizes, int n_in,
                              void* d_out, int out_size, void* d_ws, size_t ws_size,
                              hipStream_t stream) {
    const float* x  = (const float*)d_in[0];
    const int*   ei = (const int*)d_in[1];
    const float* W1 = (const float*)d_in[2];
    const float* b1 = (const float*)d_in[3];
    const float* Wm = (const float*)d_in[4];
    const float* bm = (const float*)d_in[5];
    const float* Wv = (const float*)d_in[6];
    const float* bv = (const float*)d_in[7];
    float* out = (float*)d_out;

    const int* src = ei;
    const int* dst = ei + N_EDGES;

    // workspace layout (39.2 MB total)
    int*   head = (int*)d_ws;                         // N
    float* dinv = (float*)(head + N_NODES);           // N (int deg during build)
    int*   next = (int*)(dinv + N_NODES);             // E
    float* bufA = (float*)(next + N_EDGES);           // 32N: hs, later hmv (stride 20)
    float* bufB = bufA + (size_t)N_NODES * H_DIM;     // 32N: h,  later mv  (stride 20)

    const int B = 256;
    int gN  = (N_NODES + B - 1) / B;
    int gE  = (N_EDGES + B - 1) / B;
    int gN8 = (N_NODES * 8 + B - 1) / B;

    // --- adjacency (linked lists) + degrees ---
    hipMemsetAsync(head, 0xFF, N_NODES * sizeof(int), stream);   // head = -1
    hipMemsetAsync(dinv, 0,    N_NODES * sizeof(int), stream);   // deg  = 0
    k_build<<<gE, B, 0, stream>>>(dst, (int*)dinv, head, next);
    k_dinv<<<gN, B, 0, stream>>>(dinv);

    // --- layer 1 ---
    k_gemm1<<<(N_NODES + 7) / 8, B, 0, stream>>>(x, W1, dinv, bufA);           // hs
    k_gather1<<<gN8, B, 0, stream>>>(head, next, src, dinv, bufA, b1, bufB);   // h

    // --- layer 2 ---
    k_gemm2<<<gN, B, 0, stream>>>(bufB, Wm, Wv, dinv, bufA);                   // hmv
    k_gather2<<<gN8, B, 0, stream>>>(head, next, src, dinv, bufA, bm, bv, bufB); // mv

    // --- outputs ---
    k_finalize2<<<gN, B, 0, stream>>>(bufB, out);
}

// Round 4
// 414.294 us; speedup vs baseline: 2.5167x; 1.8430x over previous
//
#include <hip/hip_runtime.h>
#include <math.h>

#define N_NODES   100000
#define N_EDGES   3200000
#define D_IN      128
#define H_DIM     32
#define OUT_DIM   16
#define MV_STRIDE 20                 // padded [Wm | Wv] row stride (80 B)
#define NB        391                // buckets = ceil(N / 256), bucket = dst >> 8
#define B1        256                // blocks in pass 1 / pass 3
#define CHUNK     12500              // edges per block (256 * 12500 = 3.2M exact)

// ---------------- pass 1: bucket histogram (LDS, no global atomics) ----------------

__global__ __launch_bounds__(256) void k_p1_hist(const int* __restrict__ dst,
                                                 int* __restrict__ hist_g) {
    __shared__ int hist[NB];
    int t = threadIdx.x;
    for (int i = t; i < NB; i += 256) hist[i] = 0;
    __syncthreads();
    int base = blockIdx.x * CHUNK;
    for (int k = t; k < CHUNK; k += 256) {
        int e = base + k;
        if (e < N_EDGES) atomicAdd(&hist[dst[e] >> 8], 1);   // LDS atomic
    }
    __syncthreads();
    for (int i = t; i < NB; i += 256) hist_g[i * B1 + blockIdx.x] = hist[i];
}

// ---------------- pass 2: 3-kernel exclusive scan of hist_g (NB*B1 = 100096) ----------------

__global__ __launch_bounds__(256) void k_scanA(const int* __restrict__ hist_g,
                                               int* __restrict__ sums) {
    __shared__ int s[256];
    int t = threadIdx.x;
    s[t] = hist_g[blockIdx.x * 256 + t];
    __syncthreads();
    for (int off = 128; off > 0; off >>= 1) {
        if (t < off) s[t] += s[t + off];
        __syncthreads();
    }
    if (t == 0) sums[blockIdx.x] = s[0];
}

__global__ __launch_bounds__(512) void k_scanB(int* sums) {
    __shared__ int a[512], b[512];
    int t = threadIdx.x;
    a[t] = (t < NB) ? sums[t] : 0;
    __syncthreads();
    int* cur = a; int* nxt = b;
    for (int off = 1; off < 512; off <<= 1) {
        nxt[t] = cur[t] + ((t >= off) ? cur[t - off] : 0);
        __syncthreads();
        int* tmp = cur; cur = nxt; nxt = tmp;
    }
    if (t < NB) sums[t] = (t == 0) ? 0 : cur[t - 1];   // exclusive
}

__global__ __launch_bounds__(256) void k_scanC(int* hist_g, const int* __restrict__ sums) {
    __shared__ int a[256], b[256];
    int t = threadIdx.x;
    int v = hist_g[blockIdx.x * 256 + t];
    a[t] = v;
    __syncthreads();
    int* cur = a; int* nxt = b;
    for (int off = 1; off < 256; off <<= 1) {
        nxt[t] = cur[t] + ((t >= off) ? cur[t - off] : 0);
        __syncthreads();
        int* tmp = cur; cur = nxt; nxt = tmp;
    }
    hist_g[blockIdx.x * 256 + t] = sums[blockIdx.x] + cur[t] - v;   // exclusive
}

// ---------------- pass 3: scatter (dst,src) pairs into bucket-segmented array ----------------

__global__ __launch_bounds__(256) void k_p3(const int* __restrict__ src,
                                            const int* __restrict__ dst,
                                            const int* __restrict__ hist_g,
                                            int2* __restrict__ pairs) {
    __shared__ int cur[NB];
    int t = threadIdx.x;
    for (int i = t; i < NB; i += 256) cur[i] = hist_g[i * B1 + blockIdx.x];
    __syncthreads();
    int base = blockIdx.x * CHUNK;
    for (int k = t; k < CHUNK; k += 256) {
        int e = base + k;
        if (e < N_EDGES) {
            int d = dst[e];
            int pos = atomicAdd(&cur[d >> 8], 1);     // LDS atomic
            pairs[pos] = make_int2(d, src[e]);
        }
    }
}

// ---------------- pass 4: per-bucket grouping by node (L2-contained scatter) ----------------
// Emits csr_src, row_ptr, dinv.

__global__ __launch_bounds__(256) void k_p4(const int2* __restrict__ pairs,
                                            const int* __restrict__ hist_g,
                                            int* __restrict__ csr_src,
                                            int* __restrict__ row_ptr,
                                            float* __restrict__ dinv) {
    __shared__ int cnt[256], a[256], b[256], cur[256];
    int t = threadIdx.x;
    int bk = blockIdx.x;
    int lo = hist_g[bk * 256];
    int hi = (bk + 1 < NB) ? hist_g[(bk + 1) * 256] : N_EDGES;

    cnt[t] = 0;
    __syncthreads();
    for (int j = lo + t; j < hi; j += 256)
        atomicAdd(&cnt[pairs[j].x & 255], 1);
    __syncthreads();

    a[t] = cnt[t];
    __syncthreads();
    int* c0 = a; int* c1 = b;
    for (int off = 1; off < 256; off <<= 1) {
        c1[t] = c0[t] + ((t >= off) ? c0[t - off] : 0);
        __syncthreads();
        int* tmp = c0; c0 = c1; c1 = tmp;
    }
    int excl = c0[t] - cnt[t];
    cur[t] = lo + excl;

    int node = bk * 256 + t;
    if (node < N_NODES) {
        row_ptr[node] = lo + excl;
        dinv[node] = rsqrtf((float)cnt[t] + 1.0f);    // +1 self-loop
    }
    if (bk == NB - 1 && t == 0) row_ptr[N_NODES] = N_EDGES;
    __syncthreads();

    for (int j = lo + t; j < hi; j += 256) {
        int2 p = pairs[j];
        int pos = atomicAdd(&cur[p.x & 255], 1);      // LDS atomic
        csr_src[pos] = p.y;                           // write within ~65KB region
    }
}

// ---------------- layer 1: hs = dinv[i] * (x @ W1) ----------------

__global__ __launch_bounds__(256) void k_gemm1(const float* __restrict__ x,
                                               const float* __restrict__ W1,
                                               const float* __restrict__ dinv,
                                               float* __restrict__ hs) {
    __shared__ float sW[D_IN * H_DIM];   // 16 KB
    int tid = threadIdx.x;
    for (int k = tid; k < D_IN * H_DIM; k += 256) sW[k] = W1[k];
    __syncthreads();

    int row = blockIdx.x * 8 + (tid >> 5);
    int j   = tid & 31;
    if (row >= N_NODES) return;

    const float* xr = x + (size_t)row * D_IN;
    float acc = 0.f;
#pragma unroll
    for (int k = 0; k < D_IN; k += 4) {
        float4 xv = *(const float4*)(xr + k);
        acc += xv.x * sW[(k + 0) * H_DIM + j];
        acc += xv.y * sW[(k + 1) * H_DIM + j];
        acc += xv.z * sW[(k + 2) * H_DIM + j];
        acc += xv.w * sW[(k + 3) * H_DIM + j];
    }
    hs[(size_t)row * H_DIM + j] = acc * dinv[row];
}

// ---------------- layer-1 aggregation: CSR gather, 8-wide MLP ----------------

__global__ __launch_bounds__(256) void k_gather1(const int* __restrict__ row_ptr,
                                                 const int* __restrict__ csr_src,
                                                 const float* __restrict__ dinv,
                                                 const float* __restrict__ hs,
                                                 const float* __restrict__ b1,
                                                 float* __restrict__ h) {
    int t = blockIdx.x * 256 + threadIdx.x;
    int i = t >> 3, c = t & 7;

    int start = row_ptr[i], end = row_ptr[i + 1];
    float4 acc = *(const float4*)(hs + (size_t)i * H_DIM + c * 4);  // self term
    int j = start;
    for (; j + 8 <= end; j += 8) {
        int s0 = csr_src[j + 0], s1 = csr_src[j + 1], s2 = csr_src[j + 2], s3 = csr_src[j + 3];
        int s4 = csr_src[j + 4], s5 = csr_src[j + 5], s6 = csr_src[j + 6], s7 = csr_src[j + 7];
        float4 v0 = *(const float4*)(hs + (size_t)s0 * H_DIM + c * 4);
        float4 v1 = *(const float4*)(hs + (size_t)s1 * H_DIM + c * 4);
        float4 v2 = *(const float4*)(hs + (size_t)s2 * H_DIM + c * 4);
        float4 v3 = *(const float4*)(hs + (size_t)s3 * H_DIM + c * 4);
        float4 v4 = *(const float4*)(hs + (size_t)s4 * H_DIM + c * 4);
        float4 v5 = *(const float4*)(hs + (size_t)s5 * H_DIM + c * 4);
        float4 v6 = *(const float4*)(hs + (size_t)s6 * H_DIM + c * 4);
        float4 v7 = *(const float4*)(hs + (size_t)s7 * H_DIM + c * 4);
        acc.x += v0.x + v1.x + v2.x + v3.x + v4.x + v5.x + v6.x + v7.x;
        acc.y += v0.y + v1.y + v2.y + v3.y + v4.y + v5.y + v6.y + v7.y;
        acc.z += v0.z + v1.z + v2.z + v3.z + v4.z + v5.z + v6.z + v7.z;
        acc.w += v0.w + v1.w + v2.w + v3.w + v4.w + v5.w + v6.w + v7.w;
    }
    for (; j < end; ++j) {
        int s = csr_src[j];
        float4 v = *(const float4*)(hs + (size_t)s * H_DIM + c * 4);
        acc.x += v.x; acc.y += v.y; acc.z += v.z; acc.w += v.w;
    }
    float di = dinv[i];
    float4 bb = *(const float4*)(b1 + c * 4);
    float4 o;
    o.x = fmaxf(di * acc.x + bb.x, 0.f);
    o.y = fmaxf(di * acc.y + bb.y, 0.f);
    o.z = fmaxf(di * acc.z + bb.z, 0.f);
    o.w = fmaxf(di * acc.w + bb.w, 0.f);
    *(float4*)(h + (size_t)i * H_DIM + c * 4) = o;
}

// ---------------- layer 2 projection: hmv = dinv[i] * (h @ [Wm|Wv]), stride 20 ----------------

__global__ __launch_bounds__(256) void k_gemm2(const float* __restrict__ h,
                                               const float* __restrict__ Wm,
                                               const float* __restrict__ Wv,
                                               const float* __restrict__ dinv,
                                               float* __restrict__ hmv) {
    __shared__ float sW[H_DIM * (OUT_DIM + 1)];
    int tid = threadIdx.x;
    for (int idx = tid; idx < H_DIM * (OUT_DIM + 1); idx += 256) {
        int k = idx / (OUT_DIM + 1), c = idx % (OUT_DIM + 1);
        sW[idx] = (c < OUT_DIM) ? Wm[k * OUT_DIM + c] : Wv[k];
    }
    __syncthreads();

    int i = blockIdx.x * 256 + tid;
    if (i >= N_NODES) return;

    float hr[H_DIM];
    const float4* hp = (const float4*)(h + (size_t)i * H_DIM);
#pragma unroll
    for (int k4 = 0; k4 < H_DIM / 4; ++k4) {
        float4 v = hp[k4];
        hr[k4 * 4 + 0] = v.x; hr[k4 * 4 + 1] = v.y;
        hr[k4 * 4 + 2] = v.z; hr[k4 * 4 + 3] = v.w;
    }
    float acc[OUT_DIM + 1];
#pragma unroll
    for (int c = 0; c <= OUT_DIM; ++c) acc[c] = 0.f;
#pragma unroll
    for (int k = 0; k < H_DIM; ++k) {
        float hv = hr[k];
#pragma unroll
        for (int c = 0; c <= OUT_DIM; ++c) acc[c] += hv * sW[k * (OUT_DIM + 1) + c];
    }
    float di = dinv[i];
    float* o = hmv + (size_t)i * MV_STRIDE;
#pragma unroll
    for (int c = 0; c <= OUT_DIM; ++c) o[c] = acc[c] * di;
}

// ---------------- layer-2 aggregation + finalize (fused) ----------------
// 8 lanes per node: lanes 0-3 handle mean cols (float4), lane 4 handles var col;
// lanes 5-7 duplicate lane-4 loads (merged) and contribute 0 to the reduction.

__global__ __launch_bounds__(256) void k_gather2f(const int* __restrict__ row_ptr,
                                                  const int* __restrict__ csr_src,
                                                  const float* __restrict__ dinv,
                                                  const float* __restrict__ hmv,
                                                  const float* __restrict__ bm,
                                                  const float* __restrict__ bv,
                                                  float* __restrict__ out) {
    int t = blockIdx.x * 256 + threadIdx.x;
    int i = t >> 3, c = t & 7;
    int ce = (c <= 4) ? c : 4;                       // clamp: lanes 5-7 mirror lane 4

    int start = row_ptr[i], end = row_ptr[i + 1];
    float4 acc = *(const float4*)(hmv + (size_t)i * MV_STRIDE + ce * 4);  // self
    int j = start;
    for (; j + 8 <= end; j += 8) {
        int s0 = csr_src[j + 0], s1 = csr_src[j + 1], s2 = csr_src[j + 2], s3 = csr_src[j + 3];
        int s4 = csr_src[j + 4], s5 = csr_src[j + 5], s6 = csr_src[j + 6], s7 = csr_src[j + 7];
        float4 v0 = *(const float4*)(hmv + (size_t)s0 * MV_STRIDE + ce * 4);
        float4 v1 = *(const float4*)(hmv + (size_t)s1 * MV_STRIDE + ce * 4);
        float4 v2 = *(const float4*)(hmv + (size_t)s2 * MV_STRIDE + ce * 4);
        float4 v3 = *(const float4*)(hmv + (size_t)s3 * MV_STRIDE + ce * 4);
        float4 v4 = *(const float4*)(hmv + (size_t)s4 * MV_STRIDE + ce * 4);
        float4 v5 = *(const float4*)(hmv + (size_t)s5 * MV_STRIDE + ce * 4);
        float4 v6 = *(const float4*)(hmv + (size_t)s6 * MV_STRIDE + ce * 4);
        float4 v7 = *(const float4*)(hmv + (size_t)s7 * MV_STRIDE + ce * 4);
        acc.x += v0.x + v1.x + v2.x + v3.x + v4.x + v5.x + v6.x + v7.x;
        acc.y += v0.y + v1.y + v2.y + v3.y + v4.y + v5.y + v6.y + v7.y;
        acc.z += v0.z + v1.z + v2.z + v3.z + v4.z + v5.z + v6.z + v7.z;
        acc.w += v0.w + v1.w + v2.w + v3.w + v4.w + v5.w + v6.w + v7.w;
    }
    for (; j < end; ++j) {
        int s = csr_src[j];
        float4 v = *(const float4*)(hmv + (size_t)s * MV_STRIDE + ce * 4);
        acc.x += v.x; acc.y += v.y; acc.z += v.z; acc.w += v.w;
    }

    float di = dinv[i];
    float4 r;
    float ssp = 0.f;
    if (c < 4) {
        float4 bb = *(const float4*)(bm + c * 4);
        r.x = di * acc.x + bb.x;
        r.y = di * acc.y + bb.y;
        r.z = di * acc.z + bb.z;
        r.w = di * acc.w + bb.w;
        ssp = r.x * r.x + r.y * r.y + r.z * r.z + r.w * r.w;
    } else {
        r.x = di * acc.x + bv[0];                    // var col (c==4 path; 5-7 discard)
    }
    // sum-of-squares across the 8-lane group (lanes >=4 contribute 0)
    ssp += __shfl_xor(ssp, 1, 8);
    ssp += __shfl_xor(ssp, 2, 8);
    ssp += __shfl_xor(ssp, 4, 8);
    float inv = rsqrtf(ssp);

    if (c < 4) {
        float4 o;
        o.x = r.x * inv; o.y = r.y * inv; o.z = r.z * inv; o.w = r.w * inv;
        *(float4*)(out + (size_t)i * OUT_DIM + c * 4) = o;
    } else if (c == 4) {
        float xv = r.x;
        float sp = fmaxf(xv, 0.f) + log1pf(expf(-fabsf(xv)));   // stable softplus
        out[(size_t)N_NODES * OUT_DIM + i] = sp + 1.0f;
    }
}

// ---------------- launch ----------------

extern "C" void kernel_launch(void* const* d_in, const int* in_sizes, int n_in,
                              void* d_out, int out_size, void* d_ws, size_t ws_size,
                              hipStream_t stream) {
    const float* x  = (const float*)d_in[0];
    const int*   ei = (const int*)d_in[1];
    const float* W1 = (const float*)d_in[2];
    const float* b1 = (const float*)d_in[3];
    const float* Wm = (const float*)d_in[4];
    const float* bm = (const float*)d_in[5];
    const float* Wv = (const float*)d_in[6];
    const float* bv = (const float*)d_in[7];
    float* out = (float*)d_out;

    const int* src = ei;
    const int* dst = ei + N_EDGES;

    // workspace layout (ints unless noted); pairs region is reused for bufA/bufB
    int*   wsi     = (int*)d_ws;
    int*   csr_src = wsi;                               // E
    int*   row_ptr = csr_src + N_EDGES;                 // N+1
    float* dinv    = (float*)(row_ptr + N_NODES + 1);   // N
    int*   hist_g  = (int*)(dinv + N_NODES);            // NB*B1 = 100096
    int*   sums    = hist_g + NB * B1;                  // 512
    size_t off     = (size_t)(sums + 512 - wsi);
    off = (off + 3) & ~(size_t)3;                       // 16B align
    int2*  pairs   = (int2*)(wsi + off);                // E int2 (25.6 MB)
    float* bufA    = (float*)pairs;                     // 32N: hs, later hmv (stride 20)
    float* bufB    = bufA + (size_t)N_NODES * H_DIM;    // 32N: h

    const int B = 256;
    int gN8 = (N_NODES * 8 + B - 1) / B;    // 3125

    // --- CSR build (no per-edge global atomics) ---
    k_p1_hist<<<B1, B, 0, stream>>>(dst, hist_g);
    k_scanA<<<NB, B, 0, stream>>>(hist_g, sums);
    k_scanB<<<1, 512, 0, stream>>>(sums);
    k_scanC<<<NB, B, 0, stream>>>(hist_g, sums);
    k_p3<<<B1, B, 0, stream>>>(src, dst, hist_g, pairs);
    k_p4<<<NB, B, 0, stream>>>(pairs, hist_g, csr_src, row_ptr, dinv);

    // --- layer 1 ---
    k_gemm1<<<(N_NODES + 7) / 8, B, 0, stream>>>(x, W1, dinv, bufA);            // hs
    k_gather1<<<gN8, B, 0, stream>>>(row_ptr, csr_src, dinv, bufA, b1, bufB);   // h

    // --- layer 2 ---
    k_gemm2<<<NB, B, 0, stream>>>(bufB, Wm, Wv, dinv, bufA);                    // hmv
    k_gather2f<<<gN8, B, 0, stream>>>(row_ptr, csr_src, dinv, bufA, bm, bv, out);
}

// Round 5
// 368.532 us; speedup vs baseline: 2.8292x; 1.1242x over previous
//
#include <hip/hip_runtime.h>
#include <math.h>

#define N_NODES   100000
#define N_EDGES   3200000
#define D_IN      128
#define H_DIM     32
#define OUT_DIM   16
#define NB        391                // buckets = ceil(N / 256), bucket = dst >> 8
#define B1        256                // blocks in pass 1 / pass 3
#define CHUNK     12500              // edges per block (256 * 12500 = 3.2M exact)

typedef _Float16 half_t;
typedef __attribute__((ext_vector_type(4))) _Float16 half4;   // 8-byte load

// ---------------- pass 1: bucket histogram (LDS, no global atomics) ----------------

__global__ __launch_bounds__(256) void k_p1_hist(const int* __restrict__ dst,
                                                 int* __restrict__ hist_g) {
    __shared__ int hist[NB];
    int t = threadIdx.x;
    for (int i = t; i < NB; i += 256) hist[i] = 0;
    __syncthreads();
    int base = blockIdx.x * CHUNK;
    for (int k = t; k < CHUNK; k += 256) {
        int e = base + k;
        if (e < N_EDGES) atomicAdd(&hist[dst[e] >> 8], 1);   // LDS atomic
    }
    __syncthreads();
    for (int i = t; i < NB; i += 256) hist_g[i * B1 + blockIdx.x] = hist[i];
}

// ---------------- pass 2: 3-kernel exclusive scan of hist_g (NB*B1 = 100096) ----------------

__global__ __launch_bounds__(256) void k_scanA(const int* __restrict__ hist_g,
                                               int* __restrict__ sums) {
    __shared__ int s[256];
    int t = threadIdx.x;
    s[t] = hist_g[blockIdx.x * 256 + t];
    __syncthreads();
    for (int off = 128; off > 0; off >>= 1) {
        if (t < off) s[t] += s[t + off];
        __syncthreads();
    }
    if (t == 0) sums[blockIdx.x] = s[0];
}

__global__ __launch_bounds__(512) void k_scanB(int* sums) {
    __shared__ int a[512], b[512];
    int t = threadIdx.x;
    a[t] = (t < NB) ? sums[t] : 0;
    __syncthreads();
    int* cur = a; int* nxt = b;
    for (int off = 1; off < 512; off <<= 1) {
        nxt[t] = cur[t] + ((t >= off) ? cur[t - off] : 0);
        __syncthreads();
        int* tmp = cur; cur = nxt; nxt = tmp;
    }
    if (t < NB) sums[t] = (t == 0) ? 0 : cur[t - 1];   // exclusive
}

__global__ __launch_bounds__(256) void k_scanC(int* hist_g, const int* __restrict__ sums) {
    __shared__ int a[256], b[256];
    int t = threadIdx.x;
    int v = hist_g[blockIdx.x * 256 + t];
    a[t] = v;
    __syncthreads();
    int* cur = a; int* nxt = b;
    for (int off = 1; off < 256; off <<= 1) {
        nxt[t] = cur[t] + ((t >= off) ? cur[t - off] : 0);
        __syncthreads();
        int* tmp = cur; cur = nxt; nxt = tmp;
    }
    hist_g[blockIdx.x * 256 + t] = sums[blockIdx.x] + cur[t] - v;   // exclusive
}

// ---------------- pass 3: scatter (dst,src) pairs into bucket-segmented array ----------------

__global__ __launch_bounds__(256) void k_p3(const int* __restrict__ src,
                                            const int* __restrict__ dst,
                                            const int* __restrict__ hist_g,
                                            int2* __restrict__ pairs) {
    __shared__ int cur[NB];
    int t = threadIdx.x;
    for (int i = t; i < NB; i += 256) cur[i] = hist_g[i * B1 + blockIdx.x];
    __syncthreads();
    int base = blockIdx.x * CHUNK;
    for (int k = t; k < CHUNK; k += 256) {
        int e = base + k;
        if (e < N_EDGES) {
            int d = dst[e];
            int pos = atomicAdd(&cur[d >> 8], 1);     // LDS atomic
            pairs[pos] = make_int2(d, src[e]);
        }
    }
}

// ---------------- pass 4: per-bucket grouping by node (L2-contained scatter) ----------------

__global__ __launch_bounds__(256) void k_p4(const int2* __restrict__ pairs,
                                            const int* __restrict__ hist_g,
                                            int* __restrict__ csr_src,
                                            int* __restrict__ row_ptr,
                                            float* __restrict__ dinv) {
    __shared__ int cnt[256], a[256], b[256], cur[256];
    int t = threadIdx.x;
    int bk = blockIdx.x;
    int lo = hist_g[bk * 256];
    int hi = (bk + 1 < NB) ? hist_g[(bk + 1) * 256] : N_EDGES;

    cnt[t] = 0;
    __syncthreads();
    for (int j = lo + t; j < hi; j += 256)
        atomicAdd(&cnt[pairs[j].x & 255], 1);
    __syncthreads();

    a[t] = cnt[t];
    __syncthreads();
    int* c0 = a; int* c1 = b;
    for (int off = 1; off < 256; off <<= 1) {
        c1[t] = c0[t] + ((t >= off) ? c0[t - off] : 0);
        __syncthreads();
        int* tmp = c0; c0 = c1; c1 = tmp;
    }
    int excl = c0[t] - cnt[t];
    cur[t] = lo + excl;

    int node = bk * 256 + t;
    if (node < N_NODES) {
        row_ptr[node] = lo + excl;
        dinv[node] = rsqrtf((float)cnt[t] + 1.0f);    // +1 self-loop
    }
    if (bk == NB - 1 && t == 0) row_ptr[N_NODES] = N_EDGES;
    __syncthreads();

    for (int j = lo + t; j < hi; j += 256) {
        int2 p = pairs[j];
        int pos = atomicAdd(&cur[p.x & 255], 1);      // LDS atomic
        csr_src[pos] = p.y;                           // write within ~65KB region
    }
}

// ---------------- layer 1: hs = fp16( dinv[i] * (x @ W1) ) ----------------

__global__ __launch_bounds__(256) void k_gemm1(const float* __restrict__ x,
                                               const float* __restrict__ W1,
                                               const float* __restrict__ dinv,
                                               half_t* __restrict__ hs) {
    __shared__ float sW[D_IN * H_DIM];   // 16 KB
    int tid = threadIdx.x;
    for (int k = tid; k < D_IN * H_DIM; k += 256) sW[k] = W1[k];
    __syncthreads();

    int row = blockIdx.x * 8 + (tid >> 5);
    int j   = tid & 31;
    if (row >= N_NODES) return;

    const float* xr = x + (size_t)row * D_IN;
    float acc = 0.f;
#pragma unroll
    for (int k = 0; k < D_IN; k += 4) {
        float4 xv = *(const float4*)(xr + k);
        acc += xv.x * sW[(k + 0) * H_DIM + j];
        acc += xv.y * sW[(k + 1) * H_DIM + j];
        acc += xv.z * sW[(k + 2) * H_DIM + j];
        acc += xv.w * sW[(k + 3) * H_DIM + j];
    }
    hs[(size_t)row * H_DIM + j] = (half_t)(acc * dinv[row]);
}

// ---------------- layer-1 aggregation: CSR gather over fp16 rows ----------------
// 8 lanes per node, lane c owns 4 cols (8B half4).

__global__ __launch_bounds__(256) void k_gather1(const int* __restrict__ row_ptr,
                                                 const int* __restrict__ csr_src,
                                                 const float* __restrict__ dinv,
                                                 const half_t* __restrict__ hs,
                                                 const float* __restrict__ b1,
                                                 half_t* __restrict__ h) {
    int t = blockIdx.x * 256 + threadIdx.x;
    int i = t >> 3, c = t & 7;

    int start = row_ptr[i], end = row_ptr[i + 1];
    half4 sv = *(const half4*)(hs + (size_t)i * H_DIM + c * 4);   // self term
    float4 acc;
    acc.x = (float)sv.x; acc.y = (float)sv.y; acc.z = (float)sv.z; acc.w = (float)sv.w;

    int j = start;
    for (; j + 8 <= end; j += 8) {
        int s0 = csr_src[j + 0], s1 = csr_src[j + 1], s2 = csr_src[j + 2], s3 = csr_src[j + 3];
        int s4 = csr_src[j + 4], s5 = csr_src[j + 5], s6 = csr_src[j + 6], s7 = csr_src[j + 7];
        half4 v0 = *(const half4*)(hs + (size_t)s0 * H_DIM + c * 4);
        half4 v1 = *(const half4*)(hs + (size_t)s1 * H_DIM + c * 4);
        half4 v2 = *(const half4*)(hs + (size_t)s2 * H_DIM + c * 4);
        half4 v3 = *(const half4*)(hs + (size_t)s3 * H_DIM + c * 4);
        half4 v4 = *(const half4*)(hs + (size_t)s4 * H_DIM + c * 4);
        half4 v5 = *(const half4*)(hs + (size_t)s5 * H_DIM + c * 4);
        half4 v6 = *(const half4*)(hs + (size_t)s6 * H_DIM + c * 4);
        half4 v7 = *(const half4*)(hs + (size_t)s7 * H_DIM + c * 4);
        acc.x += (float)v0.x + (float)v1.x + (float)v2.x + (float)v3.x
               + (float)v4.x + (float)v5.x + (float)v6.x + (float)v7.x;
        acc.y += (float)v0.y + (float)v1.y + (float)v2.y + (float)v3.y
               + (float)v4.y + (float)v5.y + (float)v6.y + (float)v7.y;
        acc.z += (float)v0.z + (float)v1.z + (float)v2.z + (float)v3.z
               + (float)v4.z + (float)v5.z + (float)v6.z + (float)v7.z;
        acc.w += (float)v0.w + (float)v1.w + (float)v2.w + (float)v3.w
               + (float)v4.w + (float)v5.w + (float)v6.w + (float)v7.w;
    }
    for (; j < end; ++j) {
        int s = csr_src[j];
        half4 v = *(const half4*)(hs + (size_t)s * H_DIM + c * 4);
        acc.x += (float)v.x; acc.y += (float)v.y; acc.z += (float)v.z; acc.w += (float)v.w;
    }

    float di = dinv[i];
    float4 bb = *(const float4*)(b1 + c * 4);
    half4 o;
    o.x = (half_t)fmaxf(di * acc.x + bb.x, 0.f);
    o.y = (half_t)fmaxf(di * acc.y + bb.y, 0.f);
    o.z = (half_t)fmaxf(di * acc.z + bb.z, 0.f);
    o.w = (half_t)fmaxf(di * acc.w + bb.w, 0.f);
    *(half4*)(h + (size_t)i * H_DIM + c * 4) = o;
}

// ---------------- layer 2 projection ----------------
// hmv (fp16, [N][16]) = dinv*(h @ Wm); varr (fp32, [N]) = dinv*(h @ Wv)

__global__ __launch_bounds__(256) void k_gemm2(const half_t* __restrict__ h,
                                               const float* __restrict__ Wm,
                                               const float* __restrict__ Wv,
                                               const float* __restrict__ dinv,
                                               half_t* __restrict__ hmv,
                                               float* __restrict__ varr) {
    __shared__ float sW[H_DIM * (OUT_DIM + 1)];
    int tid = threadIdx.x;
    for (int idx = tid; idx < H_DIM * (OUT_DIM + 1); idx += 256) {
        int k = idx / (OUT_DIM + 1), c = idx % (OUT_DIM + 1);
        sW[idx] = (c < OUT_DIM) ? Wm[k * OUT_DIM + c] : Wv[k];
    }
    __syncthreads();

    int i = blockIdx.x * 256 + tid;
    if (i >= N_NODES) return;

    float hr[H_DIM];
    const half4* hp = (const half4*)(h + (size_t)i * H_DIM);
#pragma unroll
    for (int k4 = 0; k4 < H_DIM / 4; ++k4) {
        half4 v = hp[k4];
        hr[k4 * 4 + 0] = (float)v.x; hr[k4 * 4 + 1] = (float)v.y;
        hr[k4 * 4 + 2] = (float)v.z; hr[k4 * 4 + 3] = (float)v.w;
    }
    float acc[OUT_DIM + 1];
#pragma unroll
    for (int c = 0; c <= OUT_DIM; ++c) acc[c] = 0.f;
#pragma unroll
    for (int k = 0; k < H_DIM; ++k) {
        float hv = hr[k];
#pragma unroll
        for (int c = 0; c <= OUT_DIM; ++c) acc[c] += hv * sW[k * (OUT_DIM + 1) + c];
    }
    float di = dinv[i];
    half_t* o = hmv + (size_t)i * OUT_DIM;
#pragma unroll
    for (int c4 = 0; c4 < OUT_DIM / 4; ++c4) {
        half4 ov;
        ov.x = (half_t)(acc[c4 * 4 + 0] * di);
        ov.y = (half_t)(acc[c4 * 4 + 1] * di);
        ov.z = (half_t)(acc[c4 * 4 + 2] * di);
        ov.w = (half_t)(acc[c4 * 4 + 3] * di);
        *(half4*)(o + c4 * 4) = ov;
    }
    varr[i] = acc[OUT_DIM] * di;
}

// ---------------- layer-2 aggregation + finalize (fused) ----------------
// 8 lanes per node: lanes 0-3 gather mean (8B half4 of a 32B row),
// lane 4 gathers var from the L2-resident fp32 varr; lanes 5-7 idle.

__global__ __launch_bounds__(256) void k_gather2f(const int* __restrict__ row_ptr,
                                                  const int* __restrict__ csr_src,
                                                  const float* __restrict__ dinv,
                                                  const half_t* __restrict__ hmv,
                                                  const float* __restrict__ varr,
                                                  const float* __restrict__ bm,
                                                  const float* __restrict__ bv,
                                                  float* __restrict__ out) {
    int t = blockIdx.x * 256 + threadIdx.x;
    int i = t >> 3, c = t & 7;

    int start = row_ptr[i], end = row_ptr[i + 1];
    float4 acc = make_float4(0.f, 0.f, 0.f, 0.f);
    float va = 0.f;
    if (c < 4) {
        half4 sv = *(const half4*)(hmv + (size_t)i * OUT_DIM + c * 4);
        acc.x = (float)sv.x; acc.y = (float)sv.y; acc.z = (float)sv.z; acc.w = (float)sv.w;
    } else if (c == 4) {
        va = varr[i];
    }

    int j = start;
    for (; j + 8 <= end; j += 8) {
        int s0 = csr_src[j + 0], s1 = csr_src[j + 1], s2 = csr_src[j + 2], s3 = csr_src[j + 3];
        int s4 = csr_src[j + 4], s5 = csr_src[j + 5], s6 = csr_src[j + 6], s7 = csr_src[j + 7];
        if (c < 4) {
            half4 v0 = *(const half4*)(hmv + (size_t)s0 * OUT_DIM + c * 4);
            half4 v1 = *(const half4*)(hmv + (size_t)s1 * OUT_DIM + c * 4);
            half4 v2 = *(const half4*)(hmv + (size_t)s2 * OUT_DIM + c * 4);
            half4 v3 = *(const half4*)(hmv + (size_t)s3 * OUT_DIM + c * 4);
            half4 v4 = *(const half4*)(hmv + (size_t)s4 * OUT_DIM + c * 4);
            half4 v5 = *(const half4*)(hmv + (size_t)s5 * OUT_DIM + c * 4);
            half4 v6 = *(const half4*)(hmv + (size_t)s6 * OUT_DIM + c * 4);
            half4 v7 = *(const half4*)(hmv + (size_t)s7 * OUT_DIM + c * 4);
            acc.x += (float)v0.x + (float)v1.x + (float)v2.x + (float)v3.x
                   + (float)v4.x + (float)v5.x + (float)v6.x + (float)v7.x;
            acc.y += (float)v0.y + (float)v1.y + (float)v2.y + (float)v3.y
                   + (float)v4.y + (float)v5.y + (float)v6.y + (float)v7.y;
            acc.z += (float)v0.z + (float)v1.z + (float)v2.z + (float)v3.z
                   + (float)v4.z + (float)v5.z + (float)v6.z + (float)v7.z;
            acc.w += (float)v0.w + (float)v1.w + (float)v2.w + (float)v3.w
                   + (float)v4.w + (float)v5.w + (float)v6.w + (float)v7.w;
        } else if (c == 4) {
            va += varr[s0] + varr[s1] + varr[s2] + varr[s3]
                + varr[s4] + varr[s5] + varr[s6] + varr[s7];
        }
    }
    for (; j < end; ++j) {
        int s = csr_src[j];
        if (c < 4) {
            half4 v = *(const half4*)(hmv + (size_t)s * OUT_DIM + c * 4);
            acc.x += (float)v.x; acc.y += (float)v.y; acc.z += (float)v.z; acc.w += (float)v.w;
        } else if (c == 4) {
            va += varr[s];
        }
    }

    float di = dinv[i];
    float4 r;
    float ssp = 0.f;
    if (c < 4) {
        float4 bb = *(const float4*)(bm + c * 4);
        r.x = di * acc.x + bb.x;
        r.y = di * acc.y + bb.y;
        r.z = di * acc.z + bb.z;
        r.w = di * acc.w + bb.w;
        ssp = r.x * r.x + r.y * r.y + r.z * r.z + r.w * r.w;
    }
    // sum-of-squares across the 8-lane group (lanes >=4 contribute 0)
    ssp += __shfl_xor(ssp, 1, 8);
    ssp += __shfl_xor(ssp, 2, 8);
    ssp += __shfl_xor(ssp, 4, 8);
    float inv = rsqrtf(ssp);

    if (c < 4) {
        float4 o;
        o.x = r.x * inv; o.y = r.y * inv; o.z = r.z * inv; o.w = r.w * inv;
        *(float4*)(out + (size_t)i * OUT_DIM + c * 4) = o;
    } else if (c == 4) {
        float xv = di * va + bv[0];
        float sp = fmaxf(xv, 0.f) + log1pf(expf(-fabsf(xv)));   // stable softplus
        out[(size_t)N_NODES * OUT_DIM + i] = sp + 1.0f;
    }
}

// ---------------- launch ----------------

extern "C" void kernel_launch(void* const* d_in, const int* in_sizes, int n_in,
                              void* d_out, int out_size, void* d_ws, size_t ws_size,
                              hipStream_t stream) {
    const float* x  = (const float*)d_in[0];
    const int*   ei = (const int*)d_in[1];
    const float* W1 = (const float*)d_in[2];
    const float* b1 = (const float*)d_in[3];
    const float* Wm = (const float*)d_in[4];
    const float* bm = (const float*)d_in[5];
    const float* Wv = (const float*)d_in[6];
    const float* bv = (const float*)d_in[7];
    float* out = (float*)d_out;

    const int* src = ei;
    const int* dst = ei + N_EDGES;

    // workspace layout; pairs region is reused for the fp16 feature buffers
    int*   wsi     = (int*)d_ws;
    int*   csr_src = wsi;                               // E
    int*   row_ptr = csr_src + N_EDGES;                 // N+1
    float* dinv    = (float*)(row_ptr + N_NODES + 1);   // N
    int*   hist_g  = (int*)(dinv + N_NODES);            // NB*B1 = 100096
    int*   sums    = hist_g + NB * B1;                  // 512
    size_t off     = (size_t)(sums + 512 - wsi);
    off = (off + 3) & ~(size_t)3;                       // 16B align
    int2*   pairs  = (int2*)(wsi + off);                // E int2 (25.6 MB)
    half_t* hs     = (half_t*)pairs;                    // N*32 fp16 (6.4 MB)
    half_t* h      = hs + (size_t)N_NODES * H_DIM;      // N*32 fp16 (6.4 MB)
    half_t* hmv    = h + (size_t)N_NODES * H_DIM;       // N*16 fp16 (3.2 MB)
    float*  varr   = (float*)(hmv + (size_t)N_NODES * OUT_DIM);  // N fp32

    const int B = 256;
    int gN8 = (N_NODES * 8 + B - 1) / B;    // 3125

    // --- CSR build (no per-edge global atomics) ---
    k_p1_hist<<<B1, B, 0, stream>>>(dst, hist_g);
    k_scanA<<<NB, B, 0, stream>>>(hist_g, sums);
    k_scanB<<<1, 512, 0, stream>>>(sums);
    k_scanC<<<NB, B, 0, stream>>>(hist_g, sums);
    k_p3<<<B1, B, 0, stream>>>(src, dst, hist_g, pairs);
    k_p4<<<NB, B, 0, stream>>>(pairs, hist_g, csr_src, row_ptr, dinv);

    // --- layer 1 ---
    k_gemm1<<<(N_NODES + 7) / 8, B, 0, stream>>>(x, W1, dinv, hs);
    k_gather1<<<gN8, B, 0, stream>>>(row_ptr, csr_src, dinv, hs, b1, h);

    // --- layer 2 ---
    k_gemm2<<<NB, B, 0, stream>>>(h, Wm, Wv, dinv, hmv, varr);
    k_gather2f<<<gN8, B, 0, stream>>>(row_ptr, csr_src, dinv, hmv, varr, bm, bv, out);
}

// Round 6
// 318.197 us; speedup vs baseline: 3.2768x; 1.1582x over previous
//
#include <hip/hip_runtime.h>
#include <math.h>

#define N_NODES   100000
#define N_EDGES   3200000
#define D_IN      128
#define H_DIM     32
#define OUT_DIM   16
#define NB        391                // buckets = ceil(N / 256), bucket = dst >> 8
#define B1        256                // blocks in pass 1 / pass 3
#define CHUNK     12500              // edges per block (256 * 12500 = 3.2M exact)

typedef _Float16 half_t;
typedef __attribute__((ext_vector_type(4))) _Float16 half4;   // 8-byte load

// ---------------- pass 1: bucket histogram (LDS, no global atomics) ----------------

__global__ __launch_bounds__(256) void k_p1_hist(const int* __restrict__ dst,
                                                 int* __restrict__ hist_g) {
    __shared__ int hist[NB];
    int t = threadIdx.x;
    for (int i = t; i < NB; i += 256) hist[i] = 0;
    __syncthreads();
    int base = blockIdx.x * CHUNK;
    for (int k = t; k < CHUNK; k += 256) {
        int e = base + k;
        if (e < N_EDGES) atomicAdd(&hist[dst[e] >> 8], 1);   // LDS atomic
    }
    __syncthreads();
    for (int i = t; i < NB; i += 256) hist_g[i * B1 + blockIdx.x] = hist[i];
}

// ---------------- pass 2: 3-kernel exclusive scan of hist_g (NB*B1 = 100096) ----------------

__global__ __launch_bounds__(256) void k_scanA(const int* __restrict__ hist_g,
                                               int* __restrict__ sums) {
    __shared__ int s[256];
    int t = threadIdx.x;
    s[t] = hist_g[blockIdx.x * 256 + t];
    __syncthreads();
    for (int off = 128; off > 0; off >>= 1) {
        if (t < off) s[t] += s[t + off];
        __syncthreads();
    }
    if (t == 0) sums[blockIdx.x] = s[0];
}

__global__ __launch_bounds__(512) void k_scanB(int* sums) {
    __shared__ int a[512], b[512];
    int t = threadIdx.x;
    a[t] = (t < NB) ? sums[t] : 0;
    __syncthreads();
    int* cur = a; int* nxt = b;
    for (int off = 1; off < 512; off <<= 1) {
        nxt[t] = cur[t] + ((t >= off) ? cur[t - off] : 0);
        __syncthreads();
        int* tmp = cur; cur = nxt; nxt = tmp;
    }
    if (t < NB) sums[t] = (t == 0) ? 0 : cur[t - 1];   // exclusive
}

__global__ __launch_bounds__(256) void k_scanC(int* hist_g, const int* __restrict__ sums) {
    __shared__ int a[256], b[256];
    int t = threadIdx.x;
    int v = hist_g[blockIdx.x * 256 + t];
    a[t] = v;
    __syncthreads();
    int* cur = a; int* nxt = b;
    for (int off = 1; off < 256; off <<= 1) {
        nxt[t] = cur[t] + ((t >= off) ? cur[t - off] : 0);
        __syncthreads();
        int* tmp = cur; cur = nxt; nxt = tmp;
    }
    hist_g[blockIdx.x * 256 + t] = sums[blockIdx.x] + cur[t] - v;   // exclusive
}

// ---------------- pass 3: scatter packed (dst&255,src) into bucket-segmented array ----------------
// packed pair: bits 17-24 = dst&255, bits 0-16 = src (src < 2^17)

__global__ __launch_bounds__(256) void k_p3(const int* __restrict__ src,
                                            const int* __restrict__ dst,
                                            const int* __restrict__ hist_g,
                                            unsigned int* __restrict__ pairs) {
    __shared__ int cur[NB];
    int t = threadIdx.x;
    for (int i = t; i < NB; i += 256) cur[i] = hist_g[i * B1 + blockIdx.x];
    __syncthreads();
    int base = blockIdx.x * CHUNK;
    for (int k = t; k < CHUNK; k += 256) {
        int e = base + k;
        if (e < N_EDGES) {
            int d = dst[e];
            int pos = atomicAdd(&cur[d >> 8], 1);     // LDS atomic
            pairs[pos] = ((unsigned int)(d & 255) << 17) | (unsigned int)src[e];
        }
    }
}

// ---------------- pass 4: per-bucket grouping by node (L2-contained scatter) ----------------

__global__ __launch_bounds__(256) void k_p4(const unsigned int* __restrict__ pairs,
                                            const int* __restrict__ hist_g,
                                            int* __restrict__ csr_src,
                                            int* __restrict__ row_ptr,
                                            float* __restrict__ dinv) {
    __shared__ int cnt[256], a[256], b[256], cur[256];
    int t = threadIdx.x;
    int bk = blockIdx.x;
    int lo = hist_g[bk * 256];
    int hi = (bk + 1 < NB) ? hist_g[(bk + 1) * 256] : N_EDGES;

    cnt[t] = 0;
    __syncthreads();
    for (int j = lo + t; j < hi; j += 256)
        atomicAdd(&cnt[pairs[j] >> 17], 1);
    __syncthreads();

    a[t] = cnt[t];
    __syncthreads();
    int* c0 = a; int* c1 = b;
    for (int off = 1; off < 256; off <<= 1) {
        c1[t] = c0[t] + ((t >= off) ? c0[t - off] : 0);
        __syncthreads();
        int* tmp = c0; c0 = c1; c1 = tmp;
    }
    int excl = c0[t] - cnt[t];
    cur[t] = lo + excl;

    int node = bk * 256 + t;
    if (node < N_NODES) {
        row_ptr[node] = lo + excl;
        dinv[node] = rsqrtf((float)cnt[t] + 1.0f);    // +1 self-loop
    }
    if (bk == NB - 1 && t == 0) row_ptr[N_NODES] = N_EDGES;
    __syncthreads();

    for (int j = lo + t; j < hi; j += 256) {
        unsigned int p = pairs[j];
        int pos = atomicAdd(&cur[p >> 17], 1);        // LDS atomic
        csr_src[pos] = (int)(p & 0x1FFFFu);           // write within ~65KB region
    }
}

// ---------------- layer 1: hs = fp16( dinv[i] * (x @ W1) ) ----------------
// Thread per row: acc[32] in VGPRs, W1 read UNIFORMLY -> s_load (SMEM pipe),
// no LDS at all. x streamed as float4 per thread (L1 absorbs the row stride).

__global__ __launch_bounds__(256) void k_gemm1(const float* __restrict__ x,
                                               const float* __restrict__ W1,
                                               const float* __restrict__ dinv,
                                               half_t* __restrict__ hs) {
    int i = blockIdx.x * 256 + threadIdx.x;
    if (i >= N_NODES) return;

    const float* xr = x + (size_t)i * D_IN;
    float acc[H_DIM];
#pragma unroll
    for (int c = 0; c < H_DIM; ++c) acc[c] = 0.f;

    for (int k0 = 0; k0 < D_IN; k0 += 4) {       // 32 iterations
        float4 xv = *(const float4*)(xr + k0);
#pragma unroll
        for (int kk = 0; kk < 4; ++kk) {
            float xk = (kk == 0) ? xv.x : (kk == 1) ? xv.y : (kk == 2) ? xv.z : xv.w;
            const float* wr = W1 + (k0 + kk) * H_DIM;   // uniform address -> s_load
#pragma unroll
            for (int c = 0; c < H_DIM; ++c)
                acc[c] = fmaf(xk, wr[c], acc[c]);
        }
    }

    float di = dinv[i];
    half_t* o = hs + (size_t)i * H_DIM;
#pragma unroll
    for (int c4 = 0; c4 < H_DIM / 4; ++c4) {
        half4 ov;
        ov.x = (half_t)(acc[c4 * 4 + 0] * di);
        ov.y = (half_t)(acc[c4 * 4 + 1] * di);
        ov.z = (half_t)(acc[c4 * 4 + 2] * di);
        ov.w = (half_t)(acc[c4 * 4 + 3] * di);
        *(half4*)(o + c4 * 4) = ov;
    }
}

// ---------------- layer-1 aggregation: CSR gather over fp16 rows ----------------
// 8 lanes per node, lane c owns 4 cols (8B half4).

__global__ __launch_bounds__(256) void k_gather1(const int* __restrict__ row_ptr,
                                                 const int* __restrict__ csr_src,
                                                 const float* __restrict__ dinv,
                                                 const half_t* __restrict__ hs,
                                                 const float* __restrict__ b1,
                                                 half_t* __restrict__ h) {
    int t = blockIdx.x * 256 + threadIdx.x;
    int i = t >> 3, c = t & 7;

    int start = row_ptr[i], end = row_ptr[i + 1];
    half4 sv = *(const half4*)(hs + (size_t)i * H_DIM + c * 4);   // self term
    float4 acc;
    acc.x = (float)sv.x; acc.y = (float)sv.y; acc.z = (float)sv.z; acc.w = (float)sv.w;

    int j = start;
    for (; j + 8 <= end; j += 8) {
        int s0 = csr_src[j + 0], s1 = csr_src[j + 1], s2 = csr_src[j + 2], s3 = csr_src[j + 3];
        int s4 = csr_src[j + 4], s5 = csr_src[j + 5], s6 = csr_src[j + 6], s7 = csr_src[j + 7];
        half4 v0 = *(const half4*)(hs + (size_t)s0 * H_DIM + c * 4);
        half4 v1 = *(const half4*)(hs + (size_t)s1 * H_DIM + c * 4);
        half4 v2 = *(const half4*)(hs + (size_t)s2 * H_DIM + c * 4);
        half4 v3 = *(const half4*)(hs + (size_t)s3 * H_DIM + c * 4);
        half4 v4 = *(const half4*)(hs + (size_t)s4 * H_DIM + c * 4);
        half4 v5 = *(const half4*)(hs + (size_t)s5 * H_DIM + c * 4);
        half4 v6 = *(const half4*)(hs + (size_t)s6 * H_DIM + c * 4);
        half4 v7 = *(const half4*)(hs + (size_t)s7 * H_DIM + c * 4);
        acc.x += (float)v0.x + (float)v1.x + (float)v2.x + (float)v3.x
               + (float)v4.x + (float)v5.x + (float)v6.x + (float)v7.x;
        acc.y += (float)v0.y + (float)v1.y + (float)v2.y + (float)v3.y
               + (float)v4.y + (float)v5.y + (float)v6.y + (float)v7.y;
        acc.z += (float)v0.z + (float)v1.z + (float)v2.z + (float)v3.z
               + (float)v4.z + (float)v5.z + (float)v6.z + (float)v7.z;
        acc.w += (float)v0.w + (float)v1.w + (float)v2.w + (float)v3.w
               + (float)v4.w + (float)v5.w + (float)v6.w + (float)v7.w;
    }
    for (; j < end; ++j) {
        int s = csr_src[j];
        half4 v = *(const half4*)(hs + (size_t)s * H_DIM + c * 4);
        acc.x += (float)v.x; acc.y += (float)v.y; acc.z += (float)v.z; acc.w += (float)v.w;
    }

    float di = dinv[i];
    float4 bb = *(const float4*)(b1 + c * 4);
    half4 o;
    o.x = (half_t)fmaxf(di * acc.x + bb.x, 0.f);
    o.y = (half_t)fmaxf(di * acc.y + bb.y, 0.f);
    o.z = (half_t)fmaxf(di * acc.z + bb.z, 0.f);
    o.w = (half_t)fmaxf(di * acc.w + bb.w, 0.f);
    *(half4*)(h + (size_t)i * H_DIM + c * 4) = o;
}

// ---------------- layer 2 projection ----------------
// Thread per row, W read uniformly (s_load), fully unrolled (static reg indices).
// hmv (fp16, [N][16]) = dinv*(h @ Wm); varr (fp32, [N]) = dinv*(h @ Wv)

__global__ __launch_bounds__(256) void k_gemm2(const half_t* __restrict__ h,
                                               const float* __restrict__ Wm,
                                               const float* __restrict__ Wv,
                                               const float* __restrict__ dinv,
                                               half_t* __restrict__ hmv,
                                               float* __restrict__ varr) {
    int i = blockIdx.x * 256 + threadIdx.x;
    if (i >= N_NODES) return;

    const half4* hp = (const half4*)(h + (size_t)i * H_DIM);
    float acc[OUT_DIM + 1];
#pragma unroll
    for (int c = 0; c <= OUT_DIM; ++c) acc[c] = 0.f;

#pragma unroll
    for (int k4 = 0; k4 < H_DIM / 4; ++k4) {
        half4 v = hp[k4];
#pragma unroll
        for (int kk = 0; kk < 4; ++kk) {
            int k = k4 * 4 + kk;                 // compile-time after unroll
            float hv = (kk == 0) ? (float)v.x : (kk == 1) ? (float)v.y
                     : (kk == 2) ? (float)v.z : (float)v.w;
            const float* wr = Wm + k * OUT_DIM;  // uniform -> s_load
#pragma unroll
            for (int c = 0; c < OUT_DIM; ++c)
                acc[c] = fmaf(hv, wr[c], acc[c]);
            acc[OUT_DIM] = fmaf(hv, Wv[k], acc[OUT_DIM]);
        }
    }

    float di = dinv[i];
    half_t* o = hmv + (size_t)i * OUT_DIM;
#pragma unroll
    for (int c4 = 0; c4 < OUT_DIM / 4; ++c4) {
        half4 ov;
        ov.x = (half_t)(acc[c4 * 4 + 0] * di);
        ov.y = (half_t)(acc[c4 * 4 + 1] * di);
        ov.z = (half_t)(acc[c4 * 4 + 2] * di);
        ov.w = (half_t)(acc[c4 * 4 + 3] * di);
        *(half4*)(o + c4 * 4) = ov;
    }
    varr[i] = acc[OUT_DIM] * di;
}

// ---------------- layer-2 aggregation + finalize (fused) ----------------
// 8 lanes per node: lanes 0-3 gather mean (8B half4 of a 32B row),
// lane 4 gathers var from the L2-resident fp32 varr; lanes 5-7 idle.

__global__ __launch_bounds__(256) void k_gather2f(const int* __restrict__ row_ptr,
                                                  const int* __restrict__ csr_src,
                                                  const float* __restrict__ dinv,
                                                  const half_t* __restrict__ hmv,
                                                  const float* __restrict__ varr,
                                                  const float* __restrict__ bm,
                                                  const float* __restrict__ bv,
                                                  float* __restrict__ out) {
    int t = blockIdx.x * 256 + threadIdx.x;
    int i = t >> 3, c = t & 7;

    int start = row_ptr[i], end = row_ptr[i + 1];
    float4 acc = make_float4(0.f, 0.f, 0.f, 0.f);
    float va = 0.f;
    if (c < 4) {
        half4 sv = *(const half4*)(hmv + (size_t)i * OUT_DIM + c * 4);
        acc.x = (float)sv.x; acc.y = (float)sv.y; acc.z = (float)sv.z; acc.w = (float)sv.w;
    } else if (c == 4) {
        va = varr[i];
    }

    int j = start;
    for (; j + 8 <= end; j += 8) {
        int s0 = csr_src[j + 0], s1 = csr_src[j + 1], s2 = csr_src[j + 2], s3 = csr_src[j + 3];
        int s4 = csr_src[j + 4], s5 = csr_src[j + 5], s6 = csr_src[j + 6], s7 = csr_src[j + 7];
        if (c < 4) {
            half4 v0 = *(const half4*)(hmv + (size_t)s0 * OUT_DIM + c * 4);
            half4 v1 = *(const half4*)(hmv + (size_t)s1 * OUT_DIM + c * 4);
            half4 v2 = *(const half4*)(hmv + (size_t)s2 * OUT_DIM + c * 4);
            half4 v3 = *(const half4*)(hmv + (size_t)s3 * OUT_DIM + c * 4);
            half4 v4 = *(const half4*)(hmv + (size_t)s4 * OUT_DIM + c * 4);
            half4 v5 = *(const half4*)(hmv + (size_t)s5 * OUT_DIM + c * 4);
            half4 v6 = *(const half4*)(hmv + (size_t)s6 * OUT_DIM + c * 4);
            half4 v7 = *(const half4*)(hmv + (size_t)s7 * OUT_DIM + c * 4);
            acc.x += (float)v0.x + (float)v1.x + (float)v2.x + (float)v3.x
                   + (float)v4.x + (float)v5.x + (float)v6.x + (float)v7.x;
            acc.y += (float)v0.y + (float)v1.y + (float)v2.y + (float)v3.y
                   + (float)v4.y + (float)v5.y + (float)v6.y + (float)v7.y;
            acc.z += (float)v0.z + (float)v1.z + (float)v2.z + (float)v3.z
                   + (float)v4.z + (float)v5.z + (float)v6.z + (float)v7.z;
            acc.w += (float)v0.w + (float)v1.w + (float)v2.w + (float)v3.w
                   + (float)v4.w + (float)v5.w + (float)v6.w + (float)v7.w;
        } else if (c == 4) {
            va += varr[s0] + varr[s1] + varr[s2] + varr[s3]
                + varr[s4] + varr[s5] + varr[s6] + varr[s7];
        }
    }
    for (; j < end; ++j) {
        int s = csr_src[j];
        if (c < 4) {
            half4 v = *(const half4*)(hmv + (size_t)s * OUT_DIM + c * 4);
            acc.x += (float)v.x; acc.y += (float)v.y; acc.z += (float)v.z; acc.w += (float)v.w;
        } else if (c == 4) {
            va += varr[s];
        }
    }

    float di = dinv[i];
    float4 r;
    float ssp = 0.f;
    if (c < 4) {
        float4 bb = *(const float4*)(bm + c * 4);
        r.x = di * acc.x + bb.x;
        r.y = di * acc.y + bb.y;
        r.z = di * acc.z + bb.z;
        r.w = di * acc.w + bb.w;
        ssp = r.x * r.x + r.y * r.y + r.z * r.z + r.w * r.w;
    }
    // sum-of-squares across the 8-lane group (lanes >=4 contribute 0)
    ssp += __shfl_xor(ssp, 1, 8);
    ssp += __shfl_xor(ssp, 2, 8);
    ssp += __shfl_xor(ssp, 4, 8);
    float inv = rsqrtf(ssp);

    if (c < 4) {
        float4 o;
        o.x = r.x * inv; o.y = r.y * inv; o.z = r.z * inv; o.w = r.w * inv;
        *(float4*)(out + (size_t)i * OUT_DIM + c * 4) = o;
    } else if (c == 4) {
        float xv = di * va + bv[0];
        float sp = fmaxf(xv, 0.f) + log1pf(expf(-fabsf(xv)));   // stable softplus
        out[(size_t)N_NODES * OUT_DIM + i] = sp + 1.0f;
    }
}

// ---------------- launch ----------------

extern "C" void kernel_launch(void* const* d_in, const int* in_sizes, int n_in,
                              void* d_out, int out_size, void* d_ws, size_t ws_size,
                              hipStream_t stream) {
    const float* x  = (const float*)d_in[0];
    const int*   ei = (const int*)d_in[1];
    const float* W1 = (const float*)d_in[2];
    const float* b1 = (const float*)d_in[3];
    const float* Wm = (const float*)d_in[4];
    const float* bm = (const float*)d_in[5];
    const float* Wv = (const float*)d_in[6];
    const float* bv = (const float*)d_in[7];
    float* out = (float*)d_out;

    const int* src = ei;
    const int* dst = ei + N_EDGES;

    // workspace layout; packed-pairs region is reused for the fp16 feature buffers
    int*   wsi     = (int*)d_ws;
    int*   csr_src = wsi;                               // E
    int*   row_ptr = csr_src + N_EDGES;                 // N+1
    float* dinv    = (float*)(row_ptr + N_NODES + 1);   // N
    int*   hist_g  = (int*)(dinv + N_NODES);            // NB*B1 = 100096
    int*   sums    = hist_g + NB * B1;                  // 512
    size_t off     = (size_t)(sums + 512 - wsi);
    off = (off + 3) & ~(size_t)3;                       // 16B align
    unsigned int* pairs = (unsigned int*)(wsi + off);   // E uint32 (12.8 MB)
    half_t* hs     = (half_t*)pairs;                    // N*32 fp16 (6.4 MB)
    half_t* h      = hs + (size_t)N_NODES * H_DIM;      // N*32 fp16 (6.4 MB)
    half_t* hmv    = h + (size_t)N_NODES * H_DIM;       // N*16 fp16 (3.2 MB)
    float*  varr   = (float*)(hmv + (size_t)N_NODES * OUT_DIM);  // N fp32

    const int B = 256;
    int gN  = (N_NODES + B - 1) / B;        // 391
    int gN8 = (N_NODES * 8 + B - 1) / B;    // 3125

    // --- CSR build (no per-edge global atomics) ---
    k_p1_hist<<<B1, B, 0, stream>>>(dst, hist_g);
    k_scanA<<<NB, B, 0, stream>>>(hist_g, sums);
    k_scanB<<<1, 512, 0, stream>>>(sums);
    k_scanC<<<NB, B, 0, stream>>>(hist_g, sums);
    k_p3<<<B1, B, 0, stream>>>(src, dst, hist_g, pairs);
    k_p4<<<NB, B, 0, stream>>>(pairs, hist_g, csr_src, row_ptr, dinv);

    // --- layer 1 ---
    k_gemm1<<<gN, B, 0, stream>>>(x, W1, dinv, hs);
    k_gather1<<<gN8, B, 0, stream>>>(row_ptr, csr_src, dinv, hs, b1, h);

    // --- layer 2 ---
    k_gemm2<<<gN, B, 0, stream>>>(h, Wm, Wv, dinv, hmv, varr);
    k_gather2f<<<gN8, B, 0, stream>>>(row_ptr, csr_src, dinv, hmv, varr, bm, bv, out);
}

// Round 7
// 314.978 us; speedup vs baseline: 3.3102x; 1.0102x over previous
//
#include <hip/hip_runtime.h>
#include <math.h>

#define N_NODES   100000
#define N_EDGES   3200000
#define D_IN      128
#define H_DIM     32
#define OUT_DIM   16
#define NB        391                // buckets = ceil(N / 256), bucket = dst >> 8
#define B1        512                // blocks in pass 1 / pass 3
#define CHUNK     6250               // edges per block (512 * 6250 = 3.2M exact)
#define NHIST     (NB * B1)          // 200192 histogram entries
#define SUMS_N    (NHIST / 256)      // 782 scan partials

typedef _Float16 half_t;
typedef __attribute__((ext_vector_type(4))) _Float16 half4;   // 8-byte
typedef __attribute__((ext_vector_type(8))) _Float16 half8;   // 16-byte

// ---------------- pass 1: bucket histogram (LDS, no global atomics) ----------------

__global__ __launch_bounds__(256) void k_p1_hist(const int* __restrict__ dst,
                                                 int* __restrict__ hist_g) {
    __shared__ int hist[NB];
    int t = threadIdx.x;
    for (int i = t; i < NB; i += 256) hist[i] = 0;
    __syncthreads();
    int base = blockIdx.x * CHUNK;
    for (int k = t; k < CHUNK; k += 256)
        atomicAdd(&hist[dst[base + k] >> 8], 1);   // LDS atomic
    __syncthreads();
    for (int i = t; i < NB; i += 256) hist_g[i * B1 + blockIdx.x] = hist[i];
}

// ---------------- pass 2: 3-kernel exclusive scan of hist_g (NHIST entries) ----------------

__global__ __launch_bounds__(256) void k_scanA(const int* __restrict__ hist_g,
                                               int* __restrict__ sums) {
    __shared__ int s[256];
    int t = threadIdx.x;
    s[t] = hist_g[blockIdx.x * 256 + t];
    __syncthreads();
    for (int off = 128; off > 0; off >>= 1) {
        if (t < off) s[t] += s[t + off];
        __syncthreads();
    }
    if (t == 0) sums[blockIdx.x] = s[0];
}

// exclusive scan of SUMS_N (=782) values: 256 threads x 4 serial each
__global__ __launch_bounds__(256) void k_scanB(int* sums) {
    __shared__ int a[256], b[256];
    int t = threadIdx.x;
    int base = t * 4;
    int v0 = (base + 0 < SUMS_N) ? sums[base + 0] : 0;
    int v1 = (base + 1 < SUMS_N) ? sums[base + 1] : 0;
    int v2 = (base + 2 < SUMS_N) ? sums[base + 2] : 0;
    int v3 = (base + 3 < SUMS_N) ? sums[base + 3] : 0;
    int i1 = v0 + v1, i2 = i1 + v2, i3 = i2 + v3;
    a[t] = i3;
    __syncthreads();
    int* cur = a; int* nxt = b;
    for (int off = 1; off < 256; off <<= 1) {
        nxt[t] = cur[t] + ((t >= off) ? cur[t - off] : 0);
        __syncthreads();
        int* tmp = cur; cur = nxt; nxt = tmp;
    }
    int excl = cur[t] - i3;                     // exclusive prefix of this chunk
    if (base + 0 < SUMS_N) sums[base + 0] = excl;
    if (base + 1 < SUMS_N) sums[base + 1] = excl + v0;
    if (base + 2 < SUMS_N) sums[base + 2] = excl + i1;
    if (base + 3 < SUMS_N) sums[base + 3] = excl + i2;
}

__global__ __launch_bounds__(256) void k_scanC(int* hist_g, const int* __restrict__ sums) {
    __shared__ int a[256], b[256];
    int t = threadIdx.x;
    int v = hist_g[blockIdx.x * 256 + t];
    a[t] = v;
    __syncthreads();
    int* cur = a; int* nxt = b;
    for (int off = 1; off < 256; off <<= 1) {
        nxt[t] = cur[t] + ((t >= off) ? cur[t - off] : 0);
        __syncthreads();
        int* tmp = cur; cur = nxt; nxt = tmp;
    }
    hist_g[blockIdx.x * 256 + t] = sums[blockIdx.x] + cur[t] - v;   // exclusive
}

// ---------------- pass 3: scatter packed (dst&255,src) into bucket-segmented array ----------------
// packed pair: bits 17-24 = dst&255, bits 0-16 = src (src < 2^17)

__global__ __launch_bounds__(256) void k_p3(const int* __restrict__ src,
                                            const int* __restrict__ dst,
                                            const int* __restrict__ hist_g,
                                            unsigned int* __restrict__ pairs) {
    __shared__ int cur[NB];
    int t = threadIdx.x;
    for (int i = t; i < NB; i += 256) cur[i] = hist_g[i * B1 + blockIdx.x];
    __syncthreads();
    int base = blockIdx.x * CHUNK;
    for (int k = t; k < CHUNK; k += 256) {
        int e = base + k;
        int d = dst[e];
        int pos = atomicAdd(&cur[d >> 8], 1);     // LDS atomic
        pairs[pos] = ((unsigned int)(d & 255) << 17) | (unsigned int)src[e];
    }
}

// ---------------- pass 4: per-bucket grouping by node (L2-contained scatter) ----------------

__global__ __launch_bounds__(512) void k_p4(const unsigned int* __restrict__ pairs,
                                            const int* __restrict__ hist_g,
                                            int* __restrict__ csr_src,
                                            int* __restrict__ row_ptr,
                                            float* __restrict__ dinv) {
    __shared__ int cnt[256], a[256], b[256], cur[256];
    int t = threadIdx.x;
    int bk = blockIdx.x;
    int lo = hist_g[bk * B1];
    int hi = (bk + 1 < NB) ? hist_g[(bk + 1) * B1] : N_EDGES;

    if (t < 256) cnt[t] = 0;
    __syncthreads();
    for (int j = lo + t; j < hi; j += 512)
        atomicAdd(&cnt[pairs[j] >> 17], 1);
    __syncthreads();

    if (t < 256) a[t] = cnt[t];
    __syncthreads();
    int* c0 = a; int* c1 = b;
    for (int off = 1; off < 256; off <<= 1) {
        if (t < 256) c1[t] = c0[t] + ((t >= off) ? c0[t - off] : 0);
        __syncthreads();
        int* tmp = c0; c0 = c1; c1 = tmp;
    }
    if (t < 256) {
        int excl = c0[t] - cnt[t];
        cur[t] = lo + excl;
        int node = bk * 256 + t;
        if (node < N_NODES) {
            row_ptr[node] = lo + excl;
            dinv[node] = rsqrtf((float)cnt[t] + 1.0f);    // +1 self-loop
        }
        if (bk == NB - 1 && t == 0) row_ptr[N_NODES] = N_EDGES;
    }
    __syncthreads();

    for (int j = lo + t; j < hi; j += 512) {
        unsigned int p = pairs[j];
        int pos = atomicAdd(&cur[p >> 17], 1);        // LDS atomic
        csr_src[pos] = (int)(p & 0x1FFFFu);           // write within ~65KB region
    }
}

// ---------------- layer 1: hs = fp16( dinv[i] * (x @ W1) ) ----------------
// Thread per row: acc[32] in VGPRs, W1 read UNIFORMLY -> s_load (SMEM pipe).

__global__ __launch_bounds__(256) void k_gemm1(const float* __restrict__ x,
                                               const float* __restrict__ W1,
                                               const float* __restrict__ dinv,
                                               half_t* __restrict__ hs) {
    int i = blockIdx.x * 256 + threadIdx.x;
    if (i >= N_NODES) return;

    const float* xr = x + (size_t)i * D_IN;
    float acc[H_DIM];
#pragma unroll
    for (int c = 0; c < H_DIM; ++c) acc[c] = 0.f;

    for (int k0 = 0; k0 < D_IN; k0 += 4) {       // 32 iterations
        float4 xv = *(const float4*)(xr + k0);
#pragma unroll
        for (int kk = 0; kk < 4; ++kk) {
            float xk = (kk == 0) ? xv.x : (kk == 1) ? xv.y : (kk == 2) ? xv.z : xv.w;
            const float* wr = W1 + (k0 + kk) * H_DIM;   // uniform address -> s_load
#pragma unroll
            for (int c = 0; c < H_DIM; ++c)
                acc[c] = fmaf(xk, wr[c], acc[c]);
        }
    }

    float di = dinv[i];
    half_t* o = hs + (size_t)i * H_DIM;
#pragma unroll
    for (int c4 = 0; c4 < H_DIM / 4; ++c4) {
        half4 ov;
        ov.x = (half_t)(acc[c4 * 4 + 0] * di);
        ov.y = (half_t)(acc[c4 * 4 + 1] * di);
        ov.z = (half_t)(acc[c4 * 4 + 2] * di);
        ov.w = (half_t)(acc[c4 * 4 + 3] * di);
        *(half4*)(o + c4 * 4) = ov;
    }
}

// ---------------- layer-1 aggregation: CSR gather, 4 lanes x half8 per node ----------------

__global__ __launch_bounds__(256) void k_gather1(const int* __restrict__ row_ptr,
                                                 const int* __restrict__ csr_src,
                                                 const float* __restrict__ dinv,
                                                 const half_t* __restrict__ hs,
                                                 const float* __restrict__ b1,
                                                 half_t* __restrict__ h) {
    int t = blockIdx.x * 256 + threadIdx.x;
    int i = t >> 2, c = t & 3;
    if (i >= N_NODES) return;

    const half8* hp = (const half8*)hs;          // row = 4 x half8
    int start = row_ptr[i], end = row_ptr[i + 1];
    half8 sv = hp[(size_t)i * 4 + c];            // self term
    float acc[8];
#pragma unroll
    for (int k = 0; k < 8; ++k) acc[k] = (float)sv[k];

    int j = start;
    for (; j + 8 <= end; j += 8) {
        int s0 = csr_src[j + 0], s1 = csr_src[j + 1], s2 = csr_src[j + 2], s3 = csr_src[j + 3];
        int s4 = csr_src[j + 4], s5 = csr_src[j + 5], s6 = csr_src[j + 6], s7 = csr_src[j + 7];
        half8 v0 = hp[(size_t)s0 * 4 + c];
        half8 v1 = hp[(size_t)s1 * 4 + c];
        half8 v2 = hp[(size_t)s2 * 4 + c];
        half8 v3 = hp[(size_t)s3 * 4 + c];
        half8 v4 = hp[(size_t)s4 * 4 + c];
        half8 v5 = hp[(size_t)s5 * 4 + c];
        half8 v6 = hp[(size_t)s6 * 4 + c];
        half8 v7 = hp[(size_t)s7 * 4 + c];
#pragma unroll
        for (int k = 0; k < 8; ++k)
            acc[k] += ((float)v0[k] + (float)v1[k] + (float)v2[k] + (float)v3[k])
                    + ((float)v4[k] + (float)v5[k] + (float)v6[k] + (float)v7[k]);
    }
    for (; j < end; ++j) {
        int s = csr_src[j];
        half8 v = hp[(size_t)s * 4 + c];
#pragma unroll
        for (int k = 0; k < 8; ++k) acc[k] += (float)v[k];
    }

    float di = dinv[i];
    float4 ba = *(const float4*)(b1 + c * 8);
    float4 bb = *(const float4*)(b1 + c * 8 + 4);
    half8 o;
    o[0] = (half_t)fmaxf(di * acc[0] + ba.x, 0.f);
    o[1] = (half_t)fmaxf(di * acc[1] + ba.y, 0.f);
    o[2] = (half_t)fmaxf(di * acc[2] + ba.z, 0.f);
    o[3] = (half_t)fmaxf(di * acc[3] + ba.w, 0.f);
    o[4] = (half_t)fmaxf(di * acc[4] + bb.x, 0.f);
    o[5] = (half_t)fmaxf(di * acc[5] + bb.y, 0.f);
    o[6] = (half_t)fmaxf(di * acc[6] + bb.z, 0.f);
    o[7] = (half_t)fmaxf(di * acc[7] + bb.w, 0.f);
    ((half8*)h)[(size_t)i * 4 + c] = o;
}

// ---------------- layer 2 projection ----------------
// Thread per row, W read uniformly (s_load), fully unrolled.
// hmv (fp16, [N][16]) = dinv*(h @ Wm); varr (fp32, [N]) = dinv*(h @ Wv)

__global__ __launch_bounds__(256) void k_gemm2(const half_t* __restrict__ h,
                                               const float* __restrict__ Wm,
                                               const float* __restrict__ Wv,
                                               const float* __restrict__ dinv,
                                               half_t* __restrict__ hmv,
                                               float* __restrict__ varr) {
    int i = blockIdx.x * 256 + threadIdx.x;
    if (i >= N_NODES) return;

    const half4* hp = (const half4*)(h + (size_t)i * H_DIM);
    float acc[OUT_DIM + 1];
#pragma unroll
    for (int c = 0; c <= OUT_DIM; ++c) acc[c] = 0.f;

#pragma unroll
    for (int k4 = 0; k4 < H_DIM / 4; ++k4) {
        half4 v = hp[k4];
#pragma unroll
        for (int kk = 0; kk < 4; ++kk) {
            int k = k4 * 4 + kk;                 // compile-time after unroll
            float hv = (kk == 0) ? (float)v.x : (kk == 1) ? (float)v.y
                     : (kk == 2) ? (float)v.z : (float)v.w;
            const float* wr = Wm + k * OUT_DIM;  // uniform -> s_load
#pragma unroll
            for (int c = 0; c < OUT_DIM; ++c)
                acc[c] = fmaf(hv, wr[c], acc[c]);
            acc[OUT_DIM] = fmaf(hv, Wv[k], acc[OUT_DIM]);
        }
    }

    float di = dinv[i];
    half_t* o = hmv + (size_t)i * OUT_DIM;
#pragma unroll
    for (int c4 = 0; c4 < OUT_DIM / 4; ++c4) {
        half4 ov;
        ov.x = (half_t)(acc[c4 * 4 + 0] * di);
        ov.y = (half_t)(acc[c4 * 4 + 1] * di);
        ov.z = (half_t)(acc[c4 * 4 + 2] * di);
        ov.w = (half_t)(acc[c4 * 4 + 3] * di);
        *(half4*)(o + c4 * 4) = ov;
    }
    varr[i] = acc[OUT_DIM] * di;
}

// ---------------- layer-2 aggregation + finalize (fused) ----------------
// 4 lanes per node (no idle lanes): lane c owns mean cols c*4..c*4+3;
// var loads distributed round-robin across lanes, shfl-reduced at the end.

__global__ __launch_bounds__(256) void k_gather2f(const int* __restrict__ row_ptr,
                                                  const int* __restrict__ csr_src,
                                                  const float* __restrict__ dinv,
                                                  const half_t* __restrict__ hmv,
                                                  const float* __restrict__ varr,
                                                  const float* __restrict__ bm,
                                                  const float* __restrict__ bv,
                                                  float* __restrict__ out) {
    int t = blockIdx.x * 256 + threadIdx.x;
    int i = t >> 2, c = t & 3;
    if (i >= N_NODES) return;

    int start = row_ptr[i], end = row_ptr[i + 1];
    half4 sv = *(const half4*)(hmv + (size_t)i * OUT_DIM + c * 4);
    float a0 = (float)sv.x, a1 = (float)sv.y, a2 = (float)sv.z, a3 = (float)sv.w;
    float va = (c == 0) ? varr[i] : 0.f;

    int j = start;
    for (; j + 4 <= end; j += 4) {
        int s0 = csr_src[j + 0], s1 = csr_src[j + 1], s2 = csr_src[j + 2], s3 = csr_src[j + 3];
        half4 v0 = *(const half4*)(hmv + (size_t)s0 * OUT_DIM + c * 4);
        half4 v1 = *(const half4*)(hmv + (size_t)s1 * OUT_DIM + c * 4);
        half4 v2 = *(const half4*)(hmv + (size_t)s2 * OUT_DIM + c * 4);
        half4 v3 = *(const half4*)(hmv + (size_t)s3 * OUT_DIM + c * 4);
        a0 += (float)v0.x + (float)v1.x + (float)v2.x + (float)v3.x;
        a1 += (float)v0.y + (float)v1.y + (float)v2.y + (float)v3.y;
        a2 += (float)v0.z + (float)v1.z + (float)v2.z + (float)v3.z;
        a3 += (float)v0.w + (float)v1.w + (float)v2.w + (float)v3.w;
        int sc = (c == 0) ? s0 : (c == 1) ? s1 : (c == 2) ? s2 : s3;
        va += varr[sc];                          // round-robin: each lane 1 load
    }
    for (; j < end; ++j) {
        int s = csr_src[j];
        half4 v = *(const half4*)(hmv + (size_t)s * OUT_DIM + c * 4);
        a0 += (float)v.x; a1 += (float)v.y; a2 += (float)v.z; a3 += (float)v.w;
        if (c == 0) va += varr[s];
    }

    float di = dinv[i];
    float4 bb = *(const float4*)(bm + c * 4);
    float r0 = di * a0 + bb.x;
    float r1 = di * a1 + bb.y;
    float r2 = di * a2 + bb.z;
    float r3 = di * a3 + bb.w;
    float ssp = r0 * r0 + r1 * r1 + r2 * r2 + r3 * r3;
    ssp += __shfl_xor(ssp, 1, 4);
    ssp += __shfl_xor(ssp, 2, 4);
    va  += __shfl_xor(va, 1, 4);
    va  += __shfl_xor(va, 2, 4);
    float inv = rsqrtf(ssp);

    float4 o;
    o.x = r0 * inv; o.y = r1 * inv; o.z = r2 * inv; o.w = r3 * inv;
    *(float4*)(out + (size_t)i * OUT_DIM + c * 4) = o;
    if (c == 0) {
        float xv = di * va + bv[0];
        float sp = fmaxf(xv, 0.f) + log1pf(expf(-fabsf(xv)));   // stable softplus
        out[(size_t)N_NODES * OUT_DIM + i] = sp + 1.0f;
    }
}

// ---------------- launch ----------------

extern "C" void kernel_launch(void* const* d_in, const int* in_sizes, int n_in,
                              void* d_out, int out_size, void* d_ws, size_t ws_size,
                              hipStream_t stream) {
    const float* x  = (const float*)d_in[0];
    const int*   ei = (const int*)d_in[1];
    const float* W1 = (const float*)d_in[2];
    const float* b1 = (const float*)d_in[3];
    const float* Wm = (const float*)d_in[4];
    const float* bm = (const float*)d_in[5];
    const float* Wv = (const float*)d_in[6];
    const float* bv = (const float*)d_in[7];
    float* out = (float*)d_out;

    const int* src = ei;
    const int* dst = ei + N_EDGES;

    // workspace layout; packed-pairs region is reused for the fp16 feature buffers
    int*   wsi     = (int*)d_ws;
    int*   csr_src = wsi;                               // E
    int*   row_ptr = csr_src + N_EDGES;                 // N+1
    float* dinv    = (float*)(row_ptr + N_NODES + 1);   // N
    int*   hist_g  = (int*)(dinv + N_NODES);            // NHIST = 200192
    int*   sums    = hist_g + NHIST;                    // 1024 (782 used)
    size_t off     = (size_t)(sums + 1024 - wsi);
    off = (off + 3) & ~(size_t)3;                       // 16B align
    unsigned int* pairs = (unsigned int*)(wsi + off);   // E uint32 (12.8 MB)
    half_t* hs     = (half_t*)pairs;                    // N*32 fp16 (6.4 MB)
    half_t* h      = hs + (size_t)N_NODES * H_DIM;      // N*32 fp16 (6.4 MB)
    half_t* hmv    = h + (size_t)N_NODES * H_DIM;       // N*16 fp16 (3.2 MB)
    float*  varr   = (float*)(hmv + (size_t)N_NODES * OUT_DIM);  // N fp32

    const int B = 256;
    int gN  = (N_NODES + B - 1) / B;        // 391
    int gN4 = (N_NODES * 4 + B - 1) / B;    // 1563

    // --- CSR build (no per-edge global atomics) ---
    k_p1_hist<<<B1, B, 0, stream>>>(dst, hist_g);
    k_scanA<<<SUMS_N, B, 0, stream>>>(hist_g, sums);
    k_scanB<<<1, B, 0, stream>>>(sums);
    k_scanC<<<SUMS_N, B, 0, stream>>>(hist_g, sums);
    k_p3<<<B1, B, 0, stream>>>(src, dst, hist_g, pairs);
    k_p4<<<NB, 512, 0, stream>>>(pairs, hist_g, csr_src, row_ptr, dinv);

    // --- layer 1 ---
    k_gemm1<<<gN, B, 0, stream>>>(x, W1, dinv, hs);
    k_gather1<<<gN4, B, 0, stream>>>(row_ptr, csr_src, dinv, hs, b1, h);

    // --- layer 2 ---
    k_gemm2<<<gN, B, 0, stream>>>(h, Wm, Wv, dinv, hmv, varr);
    k_gather2f<<<gN4, B, 0, stream>>>(row_ptr, csr_src, dinv, hmv, varr, bm, bv, out);
}

// Round 8
// 311.129 us; speedup vs baseline: 3.3512x; 1.0124x over previous
//
#include <hip/hip_runtime.h>
#include <math.h>

#define N_NODES   100000
#define N_HALF    50000              // src-half split for L2 residency
#define N_EDGES   3200000
#define D_IN      128
#define H_DIM     32
#define OUT_DIM   16
#define NB        391                // buckets = ceil(N / 256), bucket = dst >> 8
#define B1        1024               // blocks in pass 1 / pass 3
#define CHUNK     3125               // edges per block (1024 * 3125 = 3.2M exact)
#define NHIST     (NB * B1)          // 400384 histogram entries
#define SUMS_N    (NHIST / 256)      // 1564 scan partials
#define SCANB_PER ((SUMS_N + 255) / 256)   // 7

typedef _Float16 half_t;
typedef __attribute__((ext_vector_type(4))) _Float16 half4;   // 8-byte
typedef __attribute__((ext_vector_type(8))) _Float16 half8;   // 16-byte

// ---------------- pass 1: bucket histogram (LDS, no global atomics) ----------------

__global__ __launch_bounds__(256) void k_p1_hist(const int* __restrict__ dst,
                                                 int* __restrict__ hist_g) {
    __shared__ int hist[NB];
    int t = threadIdx.x;
    for (int i = t; i < NB; i += 256) hist[i] = 0;
    __syncthreads();
    int base = blockIdx.x * CHUNK;
    for (int k = t; k < CHUNK; k += 256)
        atomicAdd(&hist[dst[base + k] >> 8], 1);   // LDS atomic
    __syncthreads();
    for (int i = t; i < NB; i += 256) hist_g[i * B1 + blockIdx.x] = hist[i];
}

// ---------------- pass 2: 3-kernel exclusive scan of hist_g ----------------

__global__ __launch_bounds__(256) void k_scanA(const int* __restrict__ hist_g,
                                               int* __restrict__ sums) {
    __shared__ int s[256];
    int t = threadIdx.x;
    s[t] = hist_g[blockIdx.x * 256 + t];
    __syncthreads();
    for (int off = 128; off > 0; off >>= 1) {
        if (t < off) s[t] += s[t + off];
        __syncthreads();
    }
    if (t == 0) sums[blockIdx.x] = s[0];
}

// exclusive scan of SUMS_N values: 256 threads x SCANB_PER serial each
__global__ __launch_bounds__(256) void k_scanB(int* sums) {
    __shared__ int a[256], b[256];
    int t = threadIdx.x;
    int base = t * SCANB_PER;
    int v[SCANB_PER];
    int tot = 0;
#pragma unroll
    for (int k = 0; k < SCANB_PER; ++k) {
        v[k] = (base + k < SUMS_N) ? sums[base + k] : 0;
        tot += v[k];
    }
    a[t] = tot;
    __syncthreads();
    int* cur = a; int* nxt = b;
    for (int off = 1; off < 256; off <<= 1) {
        nxt[t] = cur[t] + ((t >= off) ? cur[t - off] : 0);
        __syncthreads();
        int* tmp = cur; cur = nxt; nxt = tmp;
    }
    int run = cur[t] - tot;                      // exclusive prefix of this chunk
#pragma unroll
    for (int k = 0; k < SCANB_PER; ++k) {
        if (base + k < SUMS_N) sums[base + k] = run;
        run += v[k];
    }
}

__global__ __launch_bounds__(256) void k_scanC(int* hist_g, const int* __restrict__ sums) {
    __shared__ int a[256], b[256];
    int t = threadIdx.x;
    int v = hist_g[blockIdx.x * 256 + t];
    a[t] = v;
    __syncthreads();
    int* cur = a; int* nxt = b;
    for (int off = 1; off < 256; off <<= 1) {
        nxt[t] = cur[t] + ((t >= off) ? cur[t - off] : 0);
        __syncthreads();
        int* tmp = cur; cur = nxt; nxt = tmp;
    }
    hist_g[blockIdx.x * 256 + t] = sums[blockIdx.x] + cur[t] - v;   // exclusive
}

// ---------------- pass 3: scatter packed (dst&255,src) into bucket-segmented array ----------------
// packed pair: bits 17-24 = dst&255, bits 0-16 = src (src < 2^17)

__global__ __launch_bounds__(256) void k_p3(const int* __restrict__ src,
                                            const int* __restrict__ dst,
                                            const int* __restrict__ hist_g,
                                            unsigned int* __restrict__ pairs) {
    __shared__ int cur[NB];
    int t = threadIdx.x;
    for (int i = t; i < NB; i += 256) cur[i] = hist_g[i * B1 + blockIdx.x];
    __syncthreads();
    int base = blockIdx.x * CHUNK;
    for (int k = t; k < CHUNK; k += 256) {
        int e = base + k;
        int d = dst[e];
        int pos = atomicAdd(&cur[d >> 8], 1);     // LDS atomic
        pairs[pos] = ((unsigned int)(d & 255) << 17) | (unsigned int)src[e];
    }
}

// ---------------- pass 4: per-bucket grouping by (node, src-half) ----------------
// 512 bins per bucket: bin = (node&255)*2 + (src >= N_HALF).
// Emits csr_src (lists partitioned low/high), row_ptr, row_mid, dinv.

__global__ __launch_bounds__(512) void k_p4(const unsigned int* __restrict__ pairs,
                                            const int* __restrict__ hist_g,
                                            int* __restrict__ csr_src,
                                            int* __restrict__ row_ptr,
                                            int* __restrict__ row_mid,
                                            float* __restrict__ dinv) {
    __shared__ int cnt[512], a[512], b[512], cur[512];
    int t = threadIdx.x;
    int bk = blockIdx.x;
    int lo = hist_g[bk * B1];
    int hi = (bk + 1 < NB) ? hist_g[(bk + 1) * B1] : N_EDGES;

    cnt[t] = 0;
    __syncthreads();
    for (int j = lo + t; j < hi; j += 512) {
        unsigned int p = pairs[j];
        int s = (int)(p & 0x1FFFFu);
        int bin = (int)((p >> 17) << 1) | (s >= N_HALF);
        atomicAdd(&cnt[bin], 1);
    }
    __syncthreads();

    a[t] = cnt[t];
    __syncthreads();
    int* c0 = a; int* c1 = b;
    for (int off = 1; off < 512; off <<= 1) {
        c1[t] = c0[t] + ((t >= off) ? c0[t - off] : 0);
        __syncthreads();
        int* tmp = c0; c0 = c1; c1 = tmp;
    }
    int excl = c0[t] - cnt[t];
    cur[t] = lo + excl;

    int node = bk * 256 + (t >> 1);
    if (node < N_NODES) {
        if ((t & 1) == 0) {
            row_ptr[node] = lo + excl;
            dinv[node] = rsqrtf((float)(cnt[t] + cnt[t + 1]) + 1.0f);  // +1 self-loop
        } else {
            row_mid[node] = lo + excl;
        }
    }
    if (bk == NB - 1 && t == 0) row_ptr[N_NODES] = N_EDGES;
    __syncthreads();

    for (int j = lo + t; j < hi; j += 512) {
        unsigned int p = pairs[j];
        int s = (int)(p & 0x1FFFFu);
        int bin = (int)((p >> 17) << 1) | (s >= N_HALF);
        int pos = atomicAdd(&cur[bin], 1);            // LDS atomic
        csr_src[pos] = s;                             // write within ~65KB region
    }
}

// ---------------- layer 1: hs = fp16( dinv[i] * (x @ W1) ) ----------------
// Thread per row: acc[32] in VGPRs, W1 read UNIFORMLY -> s_load (SMEM pipe).

__global__ __launch_bounds__(256) void k_gemm1(const float* __restrict__ x,
                                               const float* __restrict__ W1,
                                               const float* __restrict__ dinv,
                                               half_t* __restrict__ hs) {
    int i = blockIdx.x * 256 + threadIdx.x;
    if (i >= N_NODES) return;

    const float* xr = x + (size_t)i * D_IN;
    float acc[H_DIM];
#pragma unroll
    for (int c = 0; c < H_DIM; ++c) acc[c] = 0.f;

    for (int k0 = 0; k0 < D_IN; k0 += 4) {       // 32 iterations
        float4 xv = *(const float4*)(xr + k0);
#pragma unroll
        for (int kk = 0; kk < 4; ++kk) {
            float xk = (kk == 0) ? xv.x : (kk == 1) ? xv.y : (kk == 2) ? xv.z : xv.w;
            const float* wr = W1 + (k0 + kk) * H_DIM;   // uniform address -> s_load
#pragma unroll
            for (int c = 0; c < H_DIM; ++c)
                acc[c] = fmaf(xk, wr[c], acc[c]);
        }
    }

    float di = dinv[i];
    half_t* o = hs + (size_t)i * H_DIM;
#pragma unroll
    for (int c4 = 0; c4 < H_DIM / 4; ++c4) {
        half4 ov;
        ov.x = (half_t)(acc[c4 * 4 + 0] * di);
        ov.y = (half_t)(acc[c4 * 4 + 1] * di);
        ov.z = (half_t)(acc[c4 * 4 + 2] * di);
        ov.w = (half_t)(acc[c4 * 4 + 3] * di);
        *(half4*)(o + c4 * 4) = ov;
    }
}

// ---------------- layer-1 aggregation, pass A: low-half sources only ----------------
// Gathered region = hs[0..N_HALF) = 3.2 MB -> fits each XCD's 4 MB L2.
// 4 lanes x half8 per node; partial sum written fp16.

__global__ __launch_bounds__(256) void k_gather1A(const int* __restrict__ row_ptr,
                                                  const int* __restrict__ row_mid,
                                                  const int* __restrict__ csr_src,
                                                  const half_t* __restrict__ hs,
                                                  half_t* __restrict__ h_part) {
    int t = blockIdx.x * 256 + threadIdx.x;
    int i = t >> 2, c = t & 3;
    if (i >= N_NODES) return;

    const half8* hp = (const half8*)hs;
    int start = row_ptr[i], end = row_mid[i];
    float acc[8];
#pragma unroll
    for (int k = 0; k < 8; ++k) acc[k] = 0.f;

    int j = start;
    for (; j + 8 <= end; j += 8) {
        int s0 = csr_src[j + 0], s1 = csr_src[j + 1], s2 = csr_src[j + 2], s3 = csr_src[j + 3];
        int s4 = csr_src[j + 4], s5 = csr_src[j + 5], s6 = csr_src[j + 6], s7 = csr_src[j + 7];
        half8 v0 = hp[(size_t)s0 * 4 + c];
        half8 v1 = hp[(size_t)s1 * 4 + c];
        half8 v2 = hp[(size_t)s2 * 4 + c];
        half8 v3 = hp[(size_t)s3 * 4 + c];
        half8 v4 = hp[(size_t)s4 * 4 + c];
        half8 v5 = hp[(size_t)s5 * 4 + c];
        half8 v6 = hp[(size_t)s6 * 4 + c];
        half8 v7 = hp[(size_t)s7 * 4 + c];
#pragma unroll
        for (int k = 0; k < 8; ++k)
            acc[k] += ((float)v0[k] + (float)v1[k] + (float)v2[k] + (float)v3[k])
                    + ((float)v4[k] + (float)v5[k] + (float)v6[k] + (float)v7[k]);
    }
    for (; j < end; ++j) {
        int s = csr_src[j];
        half8 v = hp[(size_t)s * 4 + c];
#pragma unroll
        for (int k = 0; k < 8; ++k) acc[k] += (float)v[k];
    }

    half8 o;
#pragma unroll
    for (int k = 0; k < 8; ++k) o[k] = (half_t)acc[k];
    ((half8*)h_part)[(size_t)i * 4 + c] = o;
}

// ---------------- layer-1 aggregation, pass B: high-half + self + bias + relu ----------------

__global__ __launch_bounds__(256) void k_gather1B(const int* __restrict__ row_ptr,
                                                  const int* __restrict__ row_mid,
                                                  const int* __restrict__ csr_src,
                                                  const float* __restrict__ dinv,
                                                  const half_t* __restrict__ hs,
                                                  const half_t* __restrict__ h_part,
                                                  const float* __restrict__ b1,
                                                  half_t* __restrict__ h) {
    int t = blockIdx.x * 256 + threadIdx.x;
    int i = t >> 2, c = t & 3;
    if (i >= N_NODES) return;

    const half8* hp = (const half8*)hs;
    int start = row_mid[i], end = row_ptr[i + 1];
    half8 pv = ((const half8*)h_part)[(size_t)i * 4 + c];   // low-half partial
    half8 sv = hp[(size_t)i * 4 + c];                       // self term
    float acc[8];
#pragma unroll
    for (int k = 0; k < 8; ++k) acc[k] = (float)pv[k] + (float)sv[k];

    int j = start;
    for (; j + 8 <= end; j += 8) {
        int s0 = csr_src[j + 0], s1 = csr_src[j + 1], s2 = csr_src[j + 2], s3 = csr_src[j + 3];
        int s4 = csr_src[j + 4], s5 = csr_src[j + 5], s6 = csr_src[j + 6], s7 = csr_src[j + 7];
        half8 v0 = hp[(size_t)s0 * 4 + c];
        half8 v1 = hp[(size_t)s1 * 4 + c];
        half8 v2 = hp[(size_t)s2 * 4 + c];
        half8 v3 = hp[(size_t)s3 * 4 + c];
        half8 v4 = hp[(size_t)s4 * 4 + c];
        half8 v5 = hp[(size_t)s5 * 4 + c];
        half8 v6 = hp[(size_t)s6 * 4 + c];
        half8 v7 = hp[(size_t)s7 * 4 + c];
#pragma unroll
        for (int k = 0; k < 8; ++k)
            acc[k] += ((float)v0[k] + (float)v1[k] + (float)v2[k] + (float)v3[k])
                    + ((float)v4[k] + (float)v5[k] + (float)v6[k] + (float)v7[k]);
    }
    for (; j < end; ++j) {
        int s = csr_src[j];
        half8 v = hp[(size_t)s * 4 + c];
#pragma unroll
        for (int k = 0; k < 8; ++k) acc[k] += (float)v[k];
    }

    float di = dinv[i];
    float4 ba = *(const float4*)(b1 + c * 8);
    float4 bb = *(const float4*)(b1 + c * 8 + 4);
    half8 o;
    o[0] = (half_t)fmaxf(di * acc[0] + ba.x, 0.f);
    o[1] = (half_t)fmaxf(di * acc[1] + ba.y, 0.f);
    o[2] = (half_t)fmaxf(di * acc[2] + ba.z, 0.f);
    o[3] = (half_t)fmaxf(di * acc[3] + ba.w, 0.f);
    o[4] = (half_t)fmaxf(di * acc[4] + bb.x, 0.f);
    o[5] = (half_t)fmaxf(di * acc[5] + bb.y, 0.f);
    o[6] = (half_t)fmaxf(di * acc[6] + bb.z, 0.f);
    o[7] = (half_t)fmaxf(di * acc[7] + bb.w, 0.f);
    ((half8*)h)[(size_t)i * 4 + c] = o;
}

// ---------------- layer 2 projection ----------------
// hmv (fp16, [N][16]) = dinv*(h @ Wm); varr (fp32, [N]) = dinv*(h @ Wv)

__global__ __launch_bounds__(256) void k_gemm2(const half_t* __restrict__ h,
                                               const float* __restrict__ Wm,
                                               const float* __restrict__ Wv,
                                               const float* __restrict__ dinv,
                                               half_t* __restrict__ hmv,
                                               float* __restrict__ varr) {
    int i = blockIdx.x * 256 + threadIdx.x;
    if (i >= N_NODES) return;

    const half4* hp = (const half4*)(h + (size_t)i * H_DIM);
    float acc[OUT_DIM + 1];
#pragma unroll
    for (int c = 0; c <= OUT_DIM; ++c) acc[c] = 0.f;

#pragma unroll
    for (int k4 = 0; k4 < H_DIM / 4; ++k4) {
        half4 v = hp[k4];
#pragma unroll
        for (int kk = 0; kk < 4; ++kk) {
            int k = k4 * 4 + kk;                 // compile-time after unroll
            float hv = (kk == 0) ? (float)v.x : (kk == 1) ? (float)v.y
                     : (kk == 2) ? (float)v.z : (float)v.w;
            const float* wr = Wm + k * OUT_DIM;  // uniform -> s_load
#pragma unroll
            for (int c = 0; c < OUT_DIM; ++c)
                acc[c] = fmaf(hv, wr[c], acc[c]);
            acc[OUT_DIM] = fmaf(hv, Wv[k], acc[OUT_DIM]);
        }
    }

    float di = dinv[i];
    half_t* o = hmv + (size_t)i * OUT_DIM;
#pragma unroll
    for (int c4 = 0; c4 < OUT_DIM / 4; ++c4) {
        half4 ov;
        ov.x = (half_t)(acc[c4 * 4 + 0] * di);
        ov.y = (half_t)(acc[c4 * 4 + 1] * di);
        ov.z = (half_t)(acc[c4 * 4 + 2] * di);
        ov.w = (half_t)(acc[c4 * 4 + 3] * di);
        *(half4*)(o + c4 * 4) = ov;
    }
    varr[i] = acc[OUT_DIM] * di;
}

// ---------------- layer-2 aggregation + finalize (fused) ----------------
// hmv (3.2 MB) is per-XCD-L2-resident; 4 lanes/node, unroll 8 for MLP depth.

__global__ __launch_bounds__(256) void k_gather2f(const int* __restrict__ row_ptr,
                                                  const int* __restrict__ csr_src,
                                                  const float* __restrict__ dinv,
                                                  const half_t* __restrict__ hmv,
                                                  const float* __restrict__ varr,
                                                  const float* __restrict__ bm,
                                                  const float* __restrict__ bv,
                                                  float* __restrict__ out) {
    int t = blockIdx.x * 256 + threadIdx.x;
    int i = t >> 2, c = t & 3;
    if (i >= N_NODES) return;

    int start = row_ptr[i], end = row_ptr[i + 1];
    half4 sv = *(const half4*)(hmv + (size_t)i * OUT_DIM + c * 4);
    float a0 = (float)sv.x, a1 = (float)sv.y, a2 = (float)sv.z, a3 = (float)sv.w;
    float va = (c == 0) ? varr[i] : 0.f;

    int j = start;
    for (; j + 8 <= end; j += 8) {
        int s0 = csr_src[j + 0], s1 = csr_src[j + 1], s2 = csr_src[j + 2], s3 = csr_src[j + 3];
        int s4 = csr_src[j + 4], s5 = csr_src[j + 5], s6 = csr_src[j + 6], s7 = csr_src[j + 7];
        half4 v0 = *(const half4*)(hmv + (size_t)s0 * OUT_DIM + c * 4);
        half4 v1 = *(const half4*)(hmv + (size_t)s1 * OUT_DIM + c * 4);
        half4 v2 = *(const half4*)(hmv + (size_t)s2 * OUT_DIM + c * 4);
        half4 v3 = *(const half4*)(hmv + (size_t)s3 * OUT_DIM + c * 4);
        half4 v4 = *(const half4*)(hmv + (size_t)s4 * OUT_DIM + c * 4);
        half4 v5 = *(const half4*)(hmv + (size_t)s5 * OUT_DIM + c * 4);
        half4 v6 = *(const half4*)(hmv + (size_t)s6 * OUT_DIM + c * 4);
        half4 v7 = *(const half4*)(hmv + (size_t)s7 * OUT_DIM + c * 4);
        a0 += ((float)v0.x + (float)v1.x + (float)v2.x + (float)v3.x)
            + ((float)v4.x + (float)v5.x + (float)v6.x + (float)v7.x);
        a1 += ((float)v0.y + (float)v1.y + (float)v2.y + (float)v3.y)
            + ((float)v4.y + (float)v5.y + (float)v6.y + (float)v7.y);
        a2 += ((float)v0.z + (float)v1.z + (float)v2.z + (float)v3.z)
            + ((float)v4.z + (float)v5.z + (float)v6.z + (float)v7.z);
        a3 += ((float)v0.w + (float)v1.w + (float)v2.w + (float)v3.w)
            + ((float)v4.w + (float)v5.w + (float)v6.w + (float)v7.w);
        // var: round-robin, each lane covers 2 of the 8 edges
        int sa = (c == 0) ? s0 : (c == 1) ? s1 : (c == 2) ? s2 : s3;
        int sb = (c == 0) ? s4 : (c == 1) ? s5 : (c == 2) ? s6 : s7;
        va += varr[sa] + varr[sb];
    }
    for (; j < end; ++j) {
        int s = csr_src[j];
        half4 v = *(const half4*)(hmv + (size_t)s * OUT_DIM + c * 4);
        a0 += (float)v.x; a1 += (float)v.y; a2 += (float)v.z; a3 += (float)v.w;
        if (c == 0) va += varr[s];
    }

    float di = dinv[i];
    float4 bb = *(const float4*)(bm + c * 4);
    float r0 = di * a0 + bb.x;
    float r1 = di * a1 + bb.y;
    float r2 = di * a2 + bb.z;
    float r3 = di * a3 + bb.w;
    float ssp = r0 * r0 + r1 * r1 + r2 * r2 + r3 * r3;
    ssp += __shfl_xor(ssp, 1, 4);
    ssp += __shfl_xor(ssp, 2, 4);
    va  += __shfl_xor(va, 1, 4);
    va  += __shfl_xor(va, 2, 4);
    float inv = rsqrtf(ssp);

    float4 o;
    o.x = r0 * inv; o.y = r1 * inv; o.z = r2 * inv; o.w = r3 * inv;
    *(float4*)(out + (size_t)i * OUT_DIM + c * 4) = o;
    if (c == 0) {
        float xv = di * va + bv[0];
        float sp = fmaxf(xv, 0.f) + log1pf(expf(-fabsf(xv)));   // stable softplus
        out[(size_t)N_NODES * OUT_DIM + i] = sp + 1.0f;
    }
}

// ---------------- launch ----------------

extern "C" void kernel_launch(void* const* d_in, const int* in_sizes, int n_in,
                              void* d_out, int out_size, void* d_ws, size_t ws_size,
                              hipStream_t stream) {
    const float* x  = (const float*)d_in[0];
    const int*   ei = (const int*)d_in[1];
    const float* W1 = (const float*)d_in[2];
    const float* b1 = (const float*)d_in[3];
    const float* Wm = (const float*)d_in[4];
    const float* bm = (const float*)d_in[5];
    const float* Wv = (const float*)d_in[6];
    const float* bv = (const float*)d_in[7];
    float* out = (float*)d_out;

    const int* src = ei;
    const int* dst = ei + N_EDGES;

    // workspace layout; pairs region (12.8 MB) is exactly reused for hs + h
    int*   wsi     = (int*)d_ws;
    int*   csr_src = wsi;                               // E                (12.8 MB)
    int*   row_ptr = csr_src + N_EDGES;                 // N+1
    int*   row_mid = row_ptr + N_NODES + 1;             // N
    float* dinv    = (float*)(row_mid + N_NODES);       // N
    int*   hist_g  = (int*)(dinv + N_NODES);            // NHIST = 400384   (1.6 MB)
    int*   sums    = hist_g + NHIST;                    // 2048 (1564 used)
    size_t off     = (size_t)(sums + 2048 - wsi);
    off = (off + 3) & ~(size_t)3;                       // 16B align
    unsigned int* pairs = (unsigned int*)(wsi + off);   // E uint32 (12.8 MB)
    half_t* hs     = (half_t*)pairs;                    // N*32 fp16 (6.4 MB)  } overlay
    half_t* h      = hs + (size_t)N_NODES * H_DIM;      // N*32 fp16 (6.4 MB)  } = pairs
    half_t* hmv    = h + (size_t)N_NODES * H_DIM;       // N*16 fp16 (3.2 MB)
    float*  varr   = (float*)(hmv + (size_t)N_NODES * OUT_DIM);  // N fp32 (0.4 MB)
    half_t* h_part = (half_t*)(varr + N_NODES);         // N*32 fp16 (6.4 MB)

    const int B = 256;
    int gN  = (N_NODES + B - 1) / B;        // 391
    int gN4 = (N_NODES * 4 + B - 1) / B;    // 1563

    // --- CSR build (no per-edge global atomics) ---
    k_p1_hist<<<B1, B, 0, stream>>>(dst, hist_g);
    k_scanA<<<SUMS_N, B, 0, stream>>>(hist_g, sums);
    k_scanB<<<1, B, 0, stream>>>(sums);
    k_scanC<<<SUMS_N, B, 0, stream>>>(hist_g, sums);
    k_p3<<<B1, B, 0, stream>>>(src, dst, hist_g, pairs);
    k_p4<<<NB, 512, 0, stream>>>(pairs, hist_g, csr_src, row_ptr, row_mid, dinv);

    // --- layer 1 ---
    k_gemm1<<<gN, B, 0, stream>>>(x, W1, dinv, hs);
    k_gather1A<<<gN4, B, 0, stream>>>(row_ptr, row_mid, csr_src, hs, h_part);
    k_gather1B<<<gN4, B, 0, stream>>>(row_ptr, row_mid, csr_src, dinv, hs, h_part, b1, h);

    // --- layer 2 ---
    k_gemm2<<<gN, B, 0, stream>>>(h, Wm, Wv, dinv, hmv, varr);
    k_gather2f<<<gN4, B, 0, stream>>>(row_ptr, csr_src, dinv, hmv, varr, bm, bv, out);
}

// Round 11
// 297.142 us; speedup vs baseline: 3.5089x; 1.0471x over previous
//
#include <hip/hip_runtime.h>
#include <math.h>

#define N_NODES   100000
#define N_HALF    50000              // src-half split for L2 residency
#define N_EDGES   3200000
#define D_IN      128
#define H_DIM     32
#define OUT_DIM   16
#define NB        391                // buckets = ceil(N / 256), bucket = dst >> 8
#define B1        512                // blocks in pass 1 / pass 3
#define CHUNK     6272               // edges per block (512*6272 >= 3.2M; 16B-aligned base)
#define NHIST     (NB * B1)          // 200192 histogram entries
#define SUMS_N    (NHIST / 256)      // 782 scan partials
#define SCANB_PER 4                  // 256*4 >= 782

typedef _Float16 half_t;
typedef __attribute__((ext_vector_type(4))) _Float16 half4;   // 8-byte
typedef __attribute__((ext_vector_type(8))) _Float16 half8;   // 16-byte

#define PACK(d, s) ((((unsigned int)(d) & 255u) << 17) | (unsigned int)(s))

// ---------------- pass 1: bucket histogram (LDS atomics, int4 reads, 4-way ILP) ----------------

__global__ __launch_bounds__(256) void k_p1_hist(const int* __restrict__ dst,
                                                 int* __restrict__ hist_g) {
    __shared__ int hist[NB];
    int t = threadIdx.x;
    for (int i = t; i < NB; i += 256) hist[i] = 0;
    __syncthreads();
    int base = blockIdx.x * CHUNK;
    for (int k = t * 4; k < CHUNK; k += 1024) {
        int e = base + k;
        if (k + 4 <= CHUNK && e + 4 <= N_EDGES) {
            int4 d = *(const int4*)(dst + e);
            atomicAdd(&hist[d.x >> 8], 1);
            atomicAdd(&hist[d.y >> 8], 1);
            atomicAdd(&hist[d.z >> 8], 1);
            atomicAdd(&hist[d.w >> 8], 1);
        } else {
            for (int kk = k; kk < CHUNK && base + kk < N_EDGES; ++kk)
                atomicAdd(&hist[dst[base + kk] >> 8], 1);
        }
    }
    __syncthreads();
    for (int i = t; i < NB; i += 256) hist_g[i * B1 + blockIdx.x] = hist[i];
}

// ---------------- pass 2: 3-kernel exclusive scan of hist_g ----------------

__global__ __launch_bounds__(256) void k_scanA(const int* __restrict__ hist_g,
                                               int* __restrict__ sums) {
    __shared__ int s[256];
    int t = threadIdx.x;
    s[t] = hist_g[blockIdx.x * 256 + t];
    __syncthreads();
    for (int off = 128; off > 0; off >>= 1) {
        if (t < off) s[t] += s[t + off];
        __syncthreads();
    }
    if (t == 0) sums[blockIdx.x] = s[0];
}

__global__ __launch_bounds__(256) void k_scanB(int* sums) {
    __shared__ int a[256], b[256];
    int t = threadIdx.x;
    int base = t * SCANB_PER;
    int v[SCANB_PER];
    int tot = 0;
#pragma unroll
    for (int k = 0; k < SCANB_PER; ++k) {
        v[k] = (base + k < SUMS_N) ? sums[base + k] : 0;
        tot += v[k];
    }
    a[t] = tot;
    __syncthreads();
    int* cur = a; int* nxt = b;
    for (int off = 1; off < 256; off <<= 1) {
        nxt[t] = cur[t] + ((t >= off) ? cur[t - off] : 0);
        __syncthreads();
        int* tmp = cur; cur = nxt; nxt = tmp;
    }
    int run = cur[t] - tot;                      // exclusive prefix of this chunk
#pragma unroll
    for (int k = 0; k < SCANB_PER; ++k) {
        if (base + k < SUMS_N) sums[base + k] = run;
        run += v[k];
    }
}

__global__ __launch_bounds__(256) void k_scanC(int* hist_g, const int* __restrict__ sums) {
    __shared__ int a[256], b[256];
    int t = threadIdx.x;
    int v = hist_g[blockIdx.x * 256 + t];
    a[t] = v;
    __syncthreads();
    int* cur = a; int* nxt = b;
    for (int off = 1; off < 256; off <<= 1) {
        nxt[t] = cur[t] + ((t >= off) ? cur[t - off] : 0);
        __syncthreads();
        int* tmp = cur; cur = nxt; nxt = tmp;
    }
    hist_g[blockIdx.x * 256 + t] = sums[blockIdx.x] + cur[t] - v;   // exclusive
}

// ---------------- pass 3: scatter packed pairs (int4 reads, 4 independent chains) ----------------

__global__ __launch_bounds__(256) void k_p3(const int* __restrict__ src,
                                            const int* __restrict__ dst,
                                            const int* __restrict__ hist_g,
                                            unsigned int* __restrict__ pairs) {
    __shared__ int cur[NB];
    int t = threadIdx.x;
    for (int i = t; i < NB; i += 256) cur[i] = hist_g[i * B1 + blockIdx.x];
    __syncthreads();
    int base = blockIdx.x * CHUNK;
    for (int k = t * 4; k < CHUNK; k += 1024) {
        int e = base + k;
        if (k + 4 <= CHUNK && e + 4 <= N_EDGES) {
            int4 d = *(const int4*)(dst + e);
            int4 s = *(const int4*)(src + e);
            int p0 = atomicAdd(&cur[d.x >> 8], 1);
            int p1 = atomicAdd(&cur[d.y >> 8], 1);
            int p2 = atomicAdd(&cur[d.z >> 8], 1);
            int p3 = atomicAdd(&cur[d.w >> 8], 1);
            pairs[p0] = PACK(d.x, s.x);
            pairs[p1] = PACK(d.y, s.y);
            pairs[p2] = PACK(d.z, s.z);
            pairs[p3] = PACK(d.w, s.w);
        } else {
            for (int kk = k; kk < CHUNK && base + kk < N_EDGES; ++kk) {
                int d = dst[base + kk];
                int pos = atomicAdd(&cur[d >> 8], 1);
                pairs[pos] = PACK(d, src[base + kk]);
            }
        }
    }
}

// ---------------- pass 4: per-bucket grouping by (node, src-half), 2-way ILP ----------------

__global__ __launch_bounds__(512) void k_p4(const unsigned int* __restrict__ pairs,
                                            const int* __restrict__ hist_g,
                                            int* __restrict__ csr_src,
                                            int* __restrict__ row_ptr,
                                            int* __restrict__ row_mid,
                                            float* __restrict__ dinv) {
    __shared__ int cnt[512], a[512], b[512], cur[512];
    int t = threadIdx.x;
    int bk = blockIdx.x;
    int lo = hist_g[bk * B1];
    int hi = (bk + 1 < NB) ? hist_g[(bk + 1) * B1] : N_EDGES;

    cnt[t] = 0;
    __syncthreads();
    {
        int j = lo + t;
        for (; j + 512 < hi; j += 1024) {
            unsigned int p = pairs[j], q = pairs[j + 512];
            int sp = (int)(p & 0x1FFFFu), sq = (int)(q & 0x1FFFFu);
            atomicAdd(&cnt[(int)((p >> 17) << 1) | (sp >= N_HALF)], 1);
            atomicAdd(&cnt[(int)((q >> 17) << 1) | (sq >= N_HALF)], 1);
        }
        for (; j < hi; j += 512) {
            unsigned int p = pairs[j];
            int sp = (int)(p & 0x1FFFFu);
            atomicAdd(&cnt[(int)((p >> 17) << 1) | (sp >= N_HALF)], 1);
        }
    }
    __syncthreads();

    a[t] = cnt[t];
    __syncthreads();
    int* c0 = a; int* c1 = b;
    for (int off = 1; off < 512; off <<= 1) {
        c1[t] = c0[t] + ((t >= off) ? c0[t - off] : 0);
        __syncthreads();
        int* tmp = c0; c0 = c1; c1 = tmp;
    }
    int excl = c0[t] - cnt[t];
    cur[t] = lo + excl;

    int node = bk * 256 + (t >> 1);
    if (node < N_NODES) {
        if ((t & 1) == 0) {
            row_ptr[node] = lo + excl;
            dinv[node] = rsqrtf((float)(cnt[t] + cnt[t + 1]) + 1.0f);  // +1 self-loop
        } else {
            row_mid[node] = lo + excl;
        }
    }
    if (bk == NB - 1 && t == 0) row_ptr[N_NODES] = N_EDGES;
    __syncthreads();

    {
        int j = lo + t;
        for (; j + 512 < hi; j += 1024) {
            unsigned int p = pairs[j], q = pairs[j + 512];
            int sp = (int)(p & 0x1FFFFu), sq = (int)(q & 0x1FFFFu);
            int pp = atomicAdd(&cur[(int)((p >> 17) << 1) | (sp >= N_HALF)], 1);
            int pq = atomicAdd(&cur[(int)((q >> 17) << 1) | (sq >= N_HALF)], 1);
            csr_src[pp] = sp;
            csr_src[pq] = sq;
        }
        for (; j < hi; j += 512) {
            unsigned int p = pairs[j];
            int sp = (int)(p & 0x1FFFFu);
            int pp = atomicAdd(&cur[(int)((p >> 17) << 1) | (sp >= N_HALF)], 1);
            csr_src[pp] = sp;
        }
    }
}

// ---------------- layer 1: hs = fp16( dinv[i] * (x @ W1) ) ----------------

__global__ __launch_bounds__(256) void k_gemm1(const float* __restrict__ x,
                                               const float* __restrict__ W1,
                                               const float* __restrict__ dinv,
                                               half_t* __restrict__ hs) {
    int i = blockIdx.x * 256 + threadIdx.x;
    if (i >= N_NODES) return;

    const float* xr = x + (size_t)i * D_IN;
    float acc[H_DIM];
#pragma unroll
    for (int c = 0; c < H_DIM; ++c) acc[c] = 0.f;

    for (int k0 = 0; k0 < D_IN; k0 += 4) {       // 32 iterations
        float4 xv = *(const float4*)(xr + k0);
#pragma unroll
        for (int kk = 0; kk < 4; ++kk) {
            float xk = (kk == 0) ? xv.x : (kk == 1) ? xv.y : (kk == 2) ? xv.z : xv.w;
            const float* wr = W1 + (k0 + kk) * H_DIM;   // uniform address -> s_load
#pragma unroll
            for (int c = 0; c < H_DIM; ++c)
                acc[c] = fmaf(xk, wr[c], acc[c]);
        }
    }

    float di = dinv[i];
    half_t* o = hs + (size_t)i * H_DIM;
#pragma unroll
    for (int c4 = 0; c4 < H_DIM / 4; ++c4) {
        half4 ov;
        ov.x = (half_t)(acc[c4 * 4 + 0] * di);
        ov.y = (half_t)(acc[c4 * 4 + 1] * di);
        ov.z = (half_t)(acc[c4 * 4 + 2] * di);
        ov.w = (half_t)(acc[c4 * 4 + 3] * di);
        *(half4*)(o + c4 * 4) = ov;
    }
}

// ---------------- gather helpers: batched neighbor accumulation ----------------

__device__ __forceinline__ void acc16(const half8* __restrict__ hp,
                                      const int* __restrict__ csr, int j, int c,
                                      float acc[8]) {
    int s[16];
#pragma unroll
    for (int u = 0; u < 16; ++u) s[u] = csr[j + u];
    half8 v[16];
#pragma unroll
    for (int u = 0; u < 16; ++u) v[u] = hp[(size_t)s[u] * 4 + c];
#pragma unroll
    for (int u = 0; u < 16; ++u)
#pragma unroll
        for (int k = 0; k < 8; ++k) acc[k] += (float)v[u][k];
}

__device__ __forceinline__ void acc4(const half8* __restrict__ hp,
                                     const int* __restrict__ csr, int j, int c,
                                     float acc[8]) {
    int s[4];
#pragma unroll
    for (int u = 0; u < 4; ++u) s[u] = csr[j + u];
    half8 v[4];
#pragma unroll
    for (int u = 0; u < 4; ++u) v[u] = hp[(size_t)s[u] * 4 + c];
#pragma unroll
    for (int u = 0; u < 4; ++u)
#pragma unroll
        for (int k = 0; k < 8; ++k) acc[k] += (float)v[u][k];
}

// ---------------- layer-1 aggregation, pass A: low-half sources only ----------------

__global__ __launch_bounds__(256) void k_gather1A(const int* __restrict__ row_ptr,
                                                  const int* __restrict__ row_mid,
                                                  const int* __restrict__ csr_src,
                                                  const half_t* __restrict__ hs,
                                                  half_t* __restrict__ h_part) {
    int t = blockIdx.x * 256 + threadIdx.x;
    int i = t >> 2, c = t & 3;
    if (i >= N_NODES) return;

    const half8* hp = (const half8*)hs;
    int start = row_ptr[i], end = row_mid[i];
    float acc[8];
#pragma unroll
    for (int k = 0; k < 8; ++k) acc[k] = 0.f;

    int j = start;
    for (; j + 16 <= end; j += 16) acc16(hp, csr_src, j, c, acc);
    for (; j + 4 <= end; j += 4)  acc4(hp, csr_src, j, c, acc);
    for (; j < end; ++j) {
        half8 v = hp[(size_t)csr_src[j] * 4 + c];
#pragma unroll
        for (int k = 0; k < 8; ++k) acc[k] += (float)v[k];
    }

    half8 o;
#pragma unroll
    for (int k = 0; k < 8; ++k) o[k] = (half_t)acc[k];
    ((half8*)h_part)[(size_t)i * 4 + c] = o;
}

// ---------------- layer-1 aggregation, pass B: high-half + self + bias + relu ----------------

__global__ __launch_bounds__(256) void k_gather1B(const int* __restrict__ row_ptr,
                                                  const int* __restrict__ row_mid,
                                                  const int* __restrict__ csr_src,
                                                  const float* __restrict__ dinv,
                                                  const half_t* __restrict__ hs,
                                                  const half_t* __restrict__ h_part,
                                                  const float* __restrict__ b1,
                                                  half_t* __restrict__ h) {
    int t = blockIdx.x * 256 + threadIdx.x;
    int i = t >> 2, c = t & 3;
    if (i >= N_NODES) return;

    const half8* hp = (const half8*)hs;
    int start = row_mid[i], end = row_ptr[i + 1];
    half8 pv = ((const half8*)h_part)[(size_t)i * 4 + c];   // low-half partial
    half8 sv = hp[(size_t)i * 4 + c];                       // self term
    float acc[8];
#pragma unroll
    for (int k = 0; k < 8; ++k) acc[k] = (float)pv[k] + (float)sv[k];

    int j = start;
    for (; j + 16 <= end; j += 16) acc16(hp, csr_src, j, c, acc);
    for (; j + 4 <= end; j += 4)  acc4(hp, csr_src, j, c, acc);
    for (; j < end; ++j) {
        half8 v = hp[(size_t)csr_src[j] * 4 + c];
#pragma unroll
        for (int k = 0; k < 8; ++k) acc[k] += (float)v[k];
    }

    float di = dinv[i];
    float4 ba = *(const float4*)(b1 + c * 8);
    float4 bb = *(const float4*)(b1 + c * 8 + 4);
    half8 o;
    o[0] = (half_t)fmaxf(di * acc[0] + ba.x, 0.f);
    o[1] = (half_t)fmaxf(di * acc[1] + ba.y, 0.f);
    o[2] = (half_t)fmaxf(di * acc[2] + ba.z, 0.f);
    o[3] = (half_t)fmaxf(di * acc[3] + ba.w, 0.f);
    o[4] = (half_t)fmaxf(di * acc[4] + bb.x, 0.f);
    o[5] = (half_t)fmaxf(di * acc[5] + bb.y, 0.f);
    o[6] = (half_t)fmaxf(di * acc[6] + bb.z, 0.f);
    o[7] = (half_t)fmaxf(di * acc[7] + bb.w, 0.f);
    ((half8*)h)[(size_t)i * 4 + c] = o;
}

// ---------------- layer 2 projection ----------------

__global__ __launch_bounds__(256) void k_gemm2(const half_t* __restrict__ h,
                                               const float* __restrict__ Wm,
                                               const float* __restrict__ Wv,
                                               const float* __restrict__ dinv,
                                               half_t* __restrict__ hmv,
                                               float* __restrict__ varr) {
    int i = blockIdx.x * 256 + threadIdx.x;
    if (i >= N_NODES) return;

    const half4* hp = (const half4*)(h + (size_t)i * H_DIM);
    float acc[OUT_DIM + 1];
#pragma unroll
    for (int c = 0; c <= OUT_DIM; ++c) acc[c] = 0.f;

#pragma unroll
    for (int k4 = 0; k4 < H_DIM / 4; ++k4) {
        half4 v = hp[k4];
#pragma unroll
        for (int kk = 0; kk < 4; ++kk) {
            int k = k4 * 4 + kk;
            float hv = (kk == 0) ? (float)v.x : (kk == 1) ? (float)v.y
                     : (kk == 2) ? (float)v.z : (float)v.w;
            const float* wr = Wm + k * OUT_DIM;  // uniform -> s_load
#pragma unroll
            for (int c = 0; c < OUT_DIM; ++c)
                acc[c] = fmaf(hv, wr[c], acc[c]);
            acc[OUT_DIM] = fmaf(hv, Wv[k], acc[OUT_DIM]);
        }
    }

    float di = dinv[i];
    half_t* o = hmv + (size_t)i * OUT_DIM;
#pragma unroll
    for (int c4 = 0; c4 < OUT_DIM / 4; ++c4) {
        half4 ov;
        ov.x = (half_t)(acc[c4 * 4 + 0] * di);
        ov.y = (half_t)(acc[c4 * 4 + 1] * di);
        ov.z = (half_t)(acc[c4 * 4 + 2] * di);
        ov.w = (half_t)(acc[c4 * 4 + 3] * di);
        *(half4*)(o + c4 * 4) = ov;
    }
    varr[i] = acc[OUT_DIM] * di;
}

// ---------------- layer-2 aggregation + finalize: 2 lanes x half8 per node ----------------

__global__ __launch_bounds__(256) void k_gather2f(const int* __restrict__ row_ptr,
                                                  const int* __restrict__ csr_src,
                                                  const float* __restrict__ dinv,
                                                  const half_t* __restrict__ hmv,
                                                  const float* __restrict__ varr,
                                                  const float* __restrict__ bm,
                                                  const float* __restrict__ bv,
                                                  float* __restrict__ out) {
    int t = blockIdx.x * 256 + threadIdx.x;
    int i = t >> 1, c = t & 1;
    if (i >= N_NODES) return;

    const half8* mp = (const half8*)hmv;         // row = 2 x half8
    int start = row_ptr[i], end = row_ptr[i + 1];
    half8 sv = mp[(size_t)i * 2 + c];
    float acc[8];
#pragma unroll
    for (int k = 0; k < 8; ++k) acc[k] = (float)sv[k];
    float va = (c == 0) ? varr[i] : 0.f;

    int j = start;
    for (; j + 8 <= end; j += 8) {
        int s[8];
#pragma unroll
        for (int u = 0; u < 8; ++u) s[u] = csr_src[j + u];
        half8 v[8];
#pragma unroll
        for (int u = 0; u < 8; ++u) v[u] = mp[(size_t)s[u] * 2 + c];
        // var: lane 0 takes even slots, lane 1 odd slots
        float va0 = varr[s[c]], va1 = varr[s[c + 2]];
        float va2 = varr[s[c + 4]], va3 = varr[s[c + 6]];
#pragma unroll
        for (int u = 0; u < 8; ++u)
#pragma unroll
            for (int k = 0; k < 8; ++k) acc[k] += (float)v[u][k];
        va += (va0 + va1) + (va2 + va3);
    }
    for (; j < end; ++j) {
        int s = csr_src[j];
        half8 v = mp[(size_t)s * 2 + c];
#pragma unroll
        for (int k = 0; k < 8; ++k) acc[k] += (float)v[k];
        if (c == 0) va += varr[s];
    }

    float di = dinv[i];
    float4 ba = *(const float4*)(bm + c * 8);
    float4 bb = *(const float4*)(bm + c * 8 + 4);
    float r[8];
    r[0] = di * acc[0] + ba.x;  r[1] = di * acc[1] + ba.y;
    r[2] = di * acc[2] + ba.z;  r[3] = di * acc[3] + ba.w;
    r[4] = di * acc[4] + bb.x;  r[5] = di * acc[5] + bb.y;
    r[6] = di * acc[6] + bb.z;  r[7] = di * acc[7] + bb.w;
    float ssp = 0.f;
#pragma unroll
    for (int k = 0; k < 8; ++k) ssp += r[k] * r[k];
    ssp += __shfl_xor(ssp, 1, 2);
    va  += __shfl_xor(va, 1, 2);
    float inv = rsqrtf(ssp);

    float* op = out + (size_t)i * OUT_DIM + c * 8;
    float4 o0, o1;
    o0.x = r[0] * inv; o0.y = r[1] * inv; o0.z = r[2] * inv; o0.w = r[3] * inv;
    o1.x = r[4] * inv; o1.y = r[5] * inv; o1.z = r[6] * inv; o1.w = r[7] * inv;
    *(float4*)op = o0;
    *(float4*)(op + 4) = o1;
    if (c == 0) {
        float xv = di * va + bv[0];
        float sp = fmaxf(xv, 0.f) + log1pf(expf(-fabsf(xv)));   // stable softplus
        out[(size_t)N_NODES * OUT_DIM + i] = sp + 1.0f;
    }
}

// ---------------- launch ----------------

extern "C" void kernel_launch(void* const* d_in, const int* in_sizes, int n_in,
                              void* d_out, int out_size, void* d_ws, size_t ws_size,
                              hipStream_t stream) {
    const float* x  = (const float*)d_in[0];
    const int*   ei = (const int*)d_in[1];
    const float* W1 = (const float*)d_in[2];
    const float* b1 = (const float*)d_in[3];
    const float* Wm = (const float*)d_in[4];
    const float* bm = (const float*)d_in[5];
    const float* Wv = (const float*)d_in[6];
    const float* bv = (const float*)d_in[7];
    float* out = (float*)d_out;

    const int* src = ei;
    const int* dst = ei + N_EDGES;

    // workspace layout; pairs region (12.8 MB) reused for hs + h
    int*   wsi     = (int*)d_ws;
    int*   csr_src = wsi;                               // E                (12.8 MB)
    int*   row_ptr = csr_src + N_EDGES;                 // N+1
    int*   row_mid = row_ptr + N_NODES + 1;             // N
    float* dinv    = (float*)(row_mid + N_NODES);       // N
    int*   hist_g  = (int*)(dinv + N_NODES);            // NHIST = 200192
    int*   sums    = hist_g + NHIST;                    // 1024 (782 used)
    size_t off     = (size_t)(sums + 1024 - wsi);
    off = (off + 3) & ~(size_t)3;                       // 16B align
    unsigned int* pairs = (unsigned int*)(wsi + off);   // E uint32 (12.8 MB)
    half_t* hs     = (half_t*)pairs;                    // N*32 fp16 (6.4 MB)  } overlay
    half_t* h      = hs + (size_t)N_NODES * H_DIM;      // N*32 fp16 (6.4 MB)  } = pairs
    half_t* hmv    = h + (size_t)N_NODES * H_DIM;       // N*16 fp16 (3.2 MB)
    float*  varr   = (float*)(hmv + (size_t)N_NODES * OUT_DIM);  // N fp32 (0.4 MB)
    half_t* h_part = (half_t*)(varr + N_NODES);         // N*32 fp16 (6.4 MB)

    const int B = 256;
    int gN  = (N_NODES + B - 1) / B;        // 391
    int gN4 = (N_NODES * 4 + B - 1) / B;    // 1563
    int gN2 = (N_NODES * 2 + B - 1) / B;    // 782

    // --- CSR build (no per-edge global atomics) ---
    k_p1_hist<<<B1, B, 0, stream>>>(dst, hist_g);
    k_scanA<<<SUMS_N, B, 0, stream>>>(hist_g, sums);
    k_scanB<<<1, B, 0, stream>>>(sums);
    k_scanC<<<SUMS_N, B, 0, stream>>>(hist_g, sums);
    k_p3<<<B1, B, 0, stream>>>(src, dst, hist_g, pairs);
    k_p4<<<NB, 512, 0, stream>>>(pairs, hist_g, csr_src, row_ptr, row_mid, dinv);

    // --- layer 1 ---
    k_gemm1<<<gN, B, 0, stream>>>(x, W1, dinv, hs);
    k_gather1A<<<gN4, B, 0, stream>>>(row_ptr, row_mid, csr_src, hs, h_part);
    k_gather1B<<<gN4, B, 0, stream>>>(row_ptr, row_mid, csr_src, dinv, hs, h_part, b1, h);

    // --- layer 2 ---
    k_gemm2<<<gN, B, 0, stream>>>(h, Wm, Wv, dinv, hmv, varr);
    k_gather2f<<<gN2, B, 0, stream>>>(row_ptr, csr_src, dinv, hmv, varr, bm, bv, out);
}

// Round 12
// 282.803 us; speedup vs baseline: 3.6869x; 1.0507x over previous
//
#include <hip/hip_runtime.h>
#include <math.h>

#define N_NODES   100000
#define N_HALF    50000              // src-half split for L2 residency
#define N_EDGES   3200000
#define D_IN      128
#define H_DIM     32
#define OUT_DIM   16
#define NB        391                // buckets = ceil(N / 256), bucket = dst >> 8
#define B1        512                // blocks in pass 1 / pass 3
#define CHUNK     6272               // edges per block (512*6272 >= 3.2M; 16B-aligned base)
#define NHIST     (NB * B1)          // 200192 histogram entries
#define SUMS_N    (NHIST / 256)      // 782 scan partials
#define SCANB_PER 4                  // 256*4 >= 782

typedef _Float16 half_t;
typedef __attribute__((ext_vector_type(4))) _Float16 half4;   // 8-byte
typedef __attribute__((ext_vector_type(8))) _Float16 half8;   // 16-byte

#define PACK(d, s) ((((unsigned int)(d) & 255u) << 17) | (unsigned int)(s))

// ---------------- pass 1: bucket histogram (LDS atomics, int4 reads, 4-way ILP) ----------------

__global__ __launch_bounds__(256) void k_p1_hist(const int* __restrict__ dst,
                                                 int* __restrict__ hist_g) {
    __shared__ int hist[NB];
    int t = threadIdx.x;
    for (int i = t; i < NB; i += 256) hist[i] = 0;
    __syncthreads();
    int base = blockIdx.x * CHUNK;
    for (int k = t * 4; k < CHUNK; k += 1024) {
        int e = base + k;
        if (k + 4 <= CHUNK && e + 4 <= N_EDGES) {
            int4 d = *(const int4*)(dst + e);
            atomicAdd(&hist[d.x >> 8], 1);
            atomicAdd(&hist[d.y >> 8], 1);
            atomicAdd(&hist[d.z >> 8], 1);
            atomicAdd(&hist[d.w >> 8], 1);
        } else {
            for (int kk = k; kk < CHUNK && base + kk < N_EDGES; ++kk)
                atomicAdd(&hist[dst[base + kk] >> 8], 1);
        }
    }
    __syncthreads();
    for (int i = t; i < NB; i += 256) hist_g[i * B1 + blockIdx.x] = hist[i];
}

// ---------------- pass 2: 3-kernel exclusive scan of hist_g ----------------

__global__ __launch_bounds__(256) void k_scanA(const int* __restrict__ hist_g,
                                               int* __restrict__ sums) {
    __shared__ int s[256];
    int t = threadIdx.x;
    s[t] = hist_g[blockIdx.x * 256 + t];
    __syncthreads();
    for (int off = 128; off > 0; off >>= 1) {
        if (t < off) s[t] += s[t + off];
        __syncthreads();
    }
    if (t == 0) sums[blockIdx.x] = s[0];
}

__global__ __launch_bounds__(256) void k_scanB(int* sums) {
    __shared__ int a[256], b[256];
    int t = threadIdx.x;
    int base = t * SCANB_PER;
    int v[SCANB_PER];
    int tot = 0;
#pragma unroll
    for (int k = 0; k < SCANB_PER; ++k) {
        v[k] = (base + k < SUMS_N) ? sums[base + k] : 0;
        tot += v[k];
    }
    a[t] = tot;
    __syncthreads();
    int* cur = a; int* nxt = b;
    for (int off = 1; off < 256; off <<= 1) {
        nxt[t] = cur[t] + ((t >= off) ? cur[t - off] : 0);
        __syncthreads();
        int* tmp = cur; cur = nxt; nxt = tmp;
    }
    int run = cur[t] - tot;                      // exclusive prefix of this chunk
#pragma unroll
    for (int k = 0; k < SCANB_PER; ++k) {
        if (base + k < SUMS_N) sums[base + k] = run;
        run += v[k];
    }
}

__global__ __launch_bounds__(256) void k_scanC(int* hist_g, const int* __restrict__ sums) {
    __shared__ int a[256], b[256];
    int t = threadIdx.x;
    int v = hist_g[blockIdx.x * 256 + t];
    a[t] = v;
    __syncthreads();
    int* cur = a; int* nxt = b;
    for (int off = 1; off < 256; off <<= 1) {
        nxt[t] = cur[t] + ((t >= off) ? cur[t - off] : 0);
        __syncthreads();
        int* tmp = cur; cur = nxt; nxt = tmp;
    }
    hist_g[blockIdx.x * 256 + t] = sums[blockIdx.x] + cur[t] - v;   // exclusive
}

// ---------------- pass 3: scatter packed pairs (int4 reads, 4 independent chains) ----------------

__global__ __launch_bounds__(256) void k_p3(const int* __restrict__ src,
                                            const int* __restrict__ dst,
                                            const int* __restrict__ hist_g,
                                            unsigned int* __restrict__ pairs) {
    __shared__ int cur[NB];
    int t = threadIdx.x;
    for (int i = t; i < NB; i += 256) cur[i] = hist_g[i * B1 + blockIdx.x];
    __syncthreads();
    int base = blockIdx.x * CHUNK;
    for (int k = t * 4; k < CHUNK; k += 1024) {
        int e = base + k;
        if (k + 4 <= CHUNK && e + 4 <= N_EDGES) {
            int4 d = *(const int4*)(dst + e);
            int4 s = *(const int4*)(src + e);
            int p0 = atomicAdd(&cur[d.x >> 8], 1);
            int p1 = atomicAdd(&cur[d.y >> 8], 1);
            int p2 = atomicAdd(&cur[d.z >> 8], 1);
            int p3 = atomicAdd(&cur[d.w >> 8], 1);
            pairs[p0] = PACK(d.x, s.x);
            pairs[p1] = PACK(d.y, s.y);
            pairs[p2] = PACK(d.z, s.z);
            pairs[p3] = PACK(d.w, s.w);
        } else {
            for (int kk = k; kk < CHUNK && base + kk < N_EDGES; ++kk) {
                int d = dst[base + kk];
                int pos = atomicAdd(&cur[d >> 8], 1);
                pairs[pos] = PACK(d, src[base + kk]);
            }
        }
    }
}

// ---------------- pass 4: per-bucket grouping by (node, src-half), 2-way ILP ----------------

__global__ __launch_bounds__(512) void k_p4(const unsigned int* __restrict__ pairs,
                                            const int* __restrict__ hist_g,
                                            int* __restrict__ csr_src,
                                            int* __restrict__ row_ptr,
                                            int* __restrict__ row_mid,
                                            float* __restrict__ dinv) {
    __shared__ int cnt[512], a[512], b[512], cur[512];
    int t = threadIdx.x;
    int bk = blockIdx.x;
    int lo = hist_g[bk * B1];
    int hi = (bk + 1 < NB) ? hist_g[(bk + 1) * B1] : N_EDGES;

    cnt[t] = 0;
    __syncthreads();
    {
        int j = lo + t;
        for (; j + 512 < hi; j += 1024) {
            unsigned int p = pairs[j], q = pairs[j + 512];
            int sp = (int)(p & 0x1FFFFu), sq = (int)(q & 0x1FFFFu);
            atomicAdd(&cnt[(int)((p >> 17) << 1) | (sp >= N_HALF)], 1);
            atomicAdd(&cnt[(int)((q >> 17) << 1) | (sq >= N_HALF)], 1);
        }
        for (; j < hi; j += 512) {
            unsigned int p = pairs[j];
            int sp = (int)(p & 0x1FFFFu);
            atomicAdd(&cnt[(int)((p >> 17) << 1) | (sp >= N_HALF)], 1);
        }
    }
    __syncthreads();

    a[t] = cnt[t];
    __syncthreads();
    int* c0 = a; int* c1 = b;
    for (int off = 1; off < 512; off <<= 1) {
        c1[t] = c0[t] + ((t >= off) ? c0[t - off] : 0);
        __syncthreads();
        int* tmp = c0; c0 = c1; c1 = tmp;
    }
    int excl = c0[t] - cnt[t];
    cur[t] = lo + excl;

    int node = bk * 256 + (t >> 1);
    if (node < N_NODES) {
        if ((t & 1) == 0) {
            row_ptr[node] = lo + excl;
            dinv[node] = rsqrtf((float)(cnt[t] + cnt[t + 1]) + 1.0f);  // +1 self-loop
        } else {
            row_mid[node] = lo + excl;
        }
    }
    if (bk == NB - 1 && t == 0) row_ptr[N_NODES] = N_EDGES;
    __syncthreads();

    {
        int j = lo + t;
        for (; j + 512 < hi; j += 1024) {
            unsigned int p = pairs[j], q = pairs[j + 512];
            int sp = (int)(p & 0x1FFFFu), sq = (int)(q & 0x1FFFFu);
            int pp = atomicAdd(&cur[(int)((p >> 17) << 1) | (sp >= N_HALF)], 1);
            int pq = atomicAdd(&cur[(int)((q >> 17) << 1) | (sq >= N_HALF)], 1);
            csr_src[pp] = sp;
            csr_src[pq] = sq;
        }
        for (; j < hi; j += 512) {
            unsigned int p = pairs[j];
            int sp = (int)(p & 0x1FFFFu);
            int pp = atomicAdd(&cur[(int)((p >> 17) << 1) | (sp >= N_HALF)], 1);
            csr_src[pp] = sp;
        }
    }
}

// ---------------- layer 1: hs = fp16( dinv[i] * (x @ W1) ) ----------------

__global__ __launch_bounds__(256) void k_gemm1(const float* __restrict__ x,
                                               const float* __restrict__ W1,
                                               const float* __restrict__ dinv,
                                               half_t* __restrict__ hs) {
    int i = blockIdx.x * 256 + threadIdx.x;
    if (i >= N_NODES) return;

    const float* xr = x + (size_t)i * D_IN;
    float acc[H_DIM];
#pragma unroll
    for (int c = 0; c < H_DIM; ++c) acc[c] = 0.f;

    for (int k0 = 0; k0 < D_IN; k0 += 4) {       // 32 iterations
        float4 xv = *(const float4*)(xr + k0);
#pragma unroll
        for (int kk = 0; kk < 4; ++kk) {
            float xk = (kk == 0) ? xv.x : (kk == 1) ? xv.y : (kk == 2) ? xv.z : xv.w;
            const float* wr = W1 + (k0 + kk) * H_DIM;   // uniform address -> s_load
#pragma unroll
            for (int c = 0; c < H_DIM; ++c)
                acc[c] = fmaf(xk, wr[c], acc[c]);
        }
    }

    float di = dinv[i];
    half_t* o = hs + (size_t)i * H_DIM;
#pragma unroll
    for (int c4 = 0; c4 < H_DIM / 4; ++c4) {
        half4 ov;
        ov.x = (half_t)(acc[c4 * 4 + 0] * di);
        ov.y = (half_t)(acc[c4 * 4 + 1] * di);
        ov.z = (half_t)(acc[c4 * 4 + 2] * di);
        ov.w = (half_t)(acc[c4 * 4 + 3] * di);
        *(half4*)(o + c4 * 4) = ov;
    }
}

// ---------------- gather helpers: batched neighbor accumulation ----------------

__device__ __forceinline__ void acc16(const half8* __restrict__ hp,
                                      const int* __restrict__ csr, int j, int c,
                                      float acc[8]) {
    int s[16];
#pragma unroll
    for (int u = 0; u < 16; ++u) s[u] = csr[j + u];
    half8 v[16];
#pragma unroll
    for (int u = 0; u < 16; ++u) v[u] = hp[(size_t)s[u] * 4 + c];
#pragma unroll
    for (int u = 0; u < 16; ++u)
#pragma unroll
        for (int k = 0; k < 8; ++k) acc[k] += (float)v[u][k];
}

__device__ __forceinline__ void acc4(const half8* __restrict__ hp,
                                     const int* __restrict__ csr, int j, int c,
                                     float acc[8]) {
    int s[4];
#pragma unroll
    for (int u = 0; u < 4; ++u) s[u] = csr[j + u];
    half8 v[4];
#pragma unroll
    for (int u = 0; u < 4; ++u) v[u] = hp[(size_t)s[u] * 4 + c];
#pragma unroll
    for (int u = 0; u < 4; ++u)
#pragma unroll
        for (int k = 0; k < 8; ++k) acc[k] += (float)v[u][k];
}

// ---------------- layer-1 aggregation, pass A: low-half sources only ----------------

__global__ __launch_bounds__(256) void k_gather1A(const int* __restrict__ row_ptr,
                                                  const int* __restrict__ row_mid,
                                                  const int* __restrict__ csr_src,
                                                  const half_t* __restrict__ hs,
                                                  half_t* __restrict__ h_part) {
    int t = blockIdx.x * 256 + threadIdx.x;
    int i = t >> 2, c = t & 3;
    if (i >= N_NODES) return;

    const half8* hp = (const half8*)hs;
    int start = row_ptr[i], end = row_mid[i];
    float acc[8];
#pragma unroll
    for (int k = 0; k < 8; ++k) acc[k] = 0.f;

    int j = start;
    for (; j + 16 <= end; j += 16) acc16(hp, csr_src, j, c, acc);
    for (; j + 4 <= end; j += 4)  acc4(hp, csr_src, j, c, acc);
    for (; j < end; ++j) {
        half8 v = hp[(size_t)csr_src[j] * 4 + c];
#pragma unroll
        for (int k = 0; k < 8; ++k) acc[k] += (float)v[k];
    }

    half8 o;
#pragma unroll
    for (int k = 0; k < 8; ++k) o[k] = (half_t)acc[k];
    ((half8*)h_part)[(size_t)i * 4 + c] = o;
}

// ---------------- layer-1 aggregation, pass B: high-half + self + bias + relu ----------------

__global__ __launch_bounds__(256) void k_gather1B(const int* __restrict__ row_ptr,
                                                  const int* __restrict__ row_mid,
                                                  const int* __restrict__ csr_src,
                                                  const float* __restrict__ dinv,
                                                  const half_t* __restrict__ hs,
                                                  const half_t* __restrict__ h_part,
                                                  const float* __restrict__ b1,
                                                  half_t* __restrict__ h) {
    int t = blockIdx.x * 256 + threadIdx.x;
    int i = t >> 2, c = t & 3;
    if (i >= N_NODES) return;

    const half8* hp = (const half8*)hs;
    int start = row_mid[i], end = row_ptr[i + 1];
    half8 pv = ((const half8*)h_part)[(size_t)i * 4 + c];   // low-half partial
    half8 sv = hp[(size_t)i * 4 + c];                       // self term
    float acc[8];
#pragma unroll
    for (int k = 0; k < 8; ++k) acc[k] = (float)pv[k] + (float)sv[k];

    int j = start;
    for (; j + 16 <= end; j += 16) acc16(hp, csr_src, j, c, acc);
    for (; j + 4 <= end; j += 4)  acc4(hp, csr_src, j, c, acc);
    for (; j < end; ++j) {
        half8 v = hp[(size_t)csr_src[j] * 4 + c];
#pragma unroll
        for (int k = 0; k < 8; ++k) acc[k] += (float)v[k];
    }

    float di = dinv[i];
    float4 ba = *(const float4*)(b1 + c * 8);
    float4 bb = *(const float4*)(b1 + c * 8 + 4);
    half8 o;
    o[0] = (half_t)fmaxf(di * acc[0] + ba.x, 0.f);
    o[1] = (half_t)fmaxf(di * acc[1] + ba.y, 0.f);
    o[2] = (half_t)fmaxf(di * acc[2] + ba.z, 0.f);
    o[3] = (half_t)fmaxf(di * acc[3] + ba.w, 0.f);
    o[4] = (half_t)fmaxf(di * acc[4] + bb.x, 0.f);
    o[5] = (half_t)fmaxf(di * acc[5] + bb.y, 0.f);
    o[6] = (half_t)fmaxf(di * acc[6] + bb.z, 0.f);
    o[7] = (half_t)fmaxf(di * acc[7] + bb.w, 0.f);
    ((half8*)h)[(size_t)i * 4 + c] = o;
}

// ---------------- layer 2 projection ----------------

__global__ __launch_bounds__(256) void k_gemm2(const half_t* __restrict__ h,
                                               const float* __restrict__ Wm,
                                               const float* __restrict__ Wv,
                                               const float* __restrict__ dinv,
                                               half_t* __restrict__ hmv,
                                               float* __restrict__ varr) {
    int i = blockIdx.x * 256 + threadIdx.x;
    if (i >= N_NODES) return;

    const half4* hp = (const half4*)(h + (size_t)i * H_DIM);
    float acc[OUT_DIM + 1];
#pragma unroll
    for (int c = 0; c <= OUT_DIM; ++c) acc[c] = 0.f;

#pragma unroll
    for (int k4 = 0; k4 < H_DIM / 4; ++k4) {
        half4 v = hp[k4];
#pragma unroll
        for (int kk = 0; kk < 4; ++kk) {
            int k = k4 * 4 + kk;
            float hv = (kk == 0) ? (float)v.x : (kk == 1) ? (float)v.y
                     : (kk == 2) ? (float)v.z : (float)v.w;
            const float* wr = Wm + k * OUT_DIM;  // uniform -> s_load
#pragma unroll
            for (int c = 0; c < OUT_DIM; ++c)
                acc[c] = fmaf(hv, wr[c], acc[c]);
            acc[OUT_DIM] = fmaf(hv, Wv[k], acc[OUT_DIM]);
        }
    }

    float di = dinv[i];
    half_t* o = hmv + (size_t)i * OUT_DIM;
#pragma unroll
    for (int c4 = 0; c4 < OUT_DIM / 4; ++c4) {
        half4 ov;
        ov.x = (half_t)(acc[c4 * 4 + 0] * di);
        ov.y = (half_t)(acc[c4 * 4 + 1] * di);
        ov.z = (half_t)(acc[c4 * 4 + 2] * di);
        ov.w = (half_t)(acc[c4 * 4 + 3] * di);
        *(half4*)(o + c4 * 4) = ov;
    }
    varr[i] = acc[OUT_DIM] * di;
}

// ---------------- layer-2 aggregation + finalize ----------------
// 4 lanes/node: lane = (sub, c). Each sub pair handles HALF the edge list
// (restores 400K threads for latency hiding); c = col-group (0-7 / 8-15),
// 16B half8 gathers; var loads spread over all 4 lanes; shfl combine.

__global__ __launch_bounds__(256) void k_gather2f(const int* __restrict__ row_ptr,
                                                  const int* __restrict__ csr_src,
                                                  const float* __restrict__ dinv,
                                                  const half_t* __restrict__ hmv,
                                                  const float* __restrict__ varr,
                                                  const float* __restrict__ bm,
                                                  const float* __restrict__ bv,
                                                  float* __restrict__ out) {
    int t = blockIdx.x * 256 + threadIdx.x;
    int i = t >> 2, sub = (t >> 1) & 1, c = t & 1;
    if (i >= N_NODES) return;

    const half8* mp = (const half8*)hmv;         // row = 2 x half8
    int start = row_ptr[i], end = row_ptr[i + 1];
    int mid = start + ((end - start) >> 1);
    int jb = (sub == 0) ? start : mid;           // this sub-pair's edge range
    int je = (sub == 0) ? mid : end;

    float acc[8];
    float va = 0.f;
    if (sub == 0) {                              // self terms once
        half8 sv = mp[(size_t)i * 2 + c];
#pragma unroll
        for (int k = 0; k < 8; ++k) acc[k] = (float)sv[k];
        if (c == 0) va = varr[i];
    } else {
#pragma unroll
        for (int k = 0; k < 8; ++k) acc[k] = 0.f;
    }

    int j = jb;
    for (; j + 8 <= je; j += 8) {
        int s[8];
#pragma unroll
        for (int u = 0; u < 8; ++u) s[u] = csr_src[j + u];
        half8 v[8];
#pragma unroll
        for (int u = 0; u < 8; ++u) v[u] = mp[(size_t)s[u] * 2 + c];
        // var: lane c takes slots with (u&1)==c -> 4 loads per lane
        float va0 = varr[s[c]],     va1 = varr[s[c + 2]];
        float va2 = varr[s[c + 4]], va3 = varr[s[c + 6]];
#pragma unroll
        for (int u = 0; u < 8; ++u)
#pragma unroll
            for (int k = 0; k < 8; ++k) acc[k] += (float)v[u][k];
        va += (va0 + va1) + (va2 + va3);
    }
    for (; j < je; ++j) {
        int s = csr_src[j];
        half8 v = mp[(size_t)s * 2 + c];
#pragma unroll
        for (int k = 0; k < 8; ++k) acc[k] += (float)v[k];
        if (((j - jb) & 1) == c) va += varr[s];
    }

    // combine the two sub halves (lane ^2)
#pragma unroll
    for (int k = 0; k < 8; ++k) acc[k] += __shfl_xor(acc[k], 2, 4);
    // var: sum over all 4 lanes
    va += __shfl_xor(va, 1, 4);
    va += __shfl_xor(va, 2, 4);

    float di = dinv[i];
    float4 ba = *(const float4*)(bm + c * 8);
    float4 bb = *(const float4*)(bm + c * 8 + 4);
    float r[8];
    r[0] = di * acc[0] + ba.x;  r[1] = di * acc[1] + ba.y;
    r[2] = di * acc[2] + ba.z;  r[3] = di * acc[3] + ba.w;
    r[4] = di * acc[4] + bb.x;  r[5] = di * acc[5] + bb.y;
    r[6] = di * acc[6] + bb.z;  r[7] = di * acc[7] + bb.w;
    float ssp = 0.f;
#pragma unroll
    for (int k = 0; k < 8; ++k) ssp += r[k] * r[k];
    ssp += __shfl_xor(ssp, 1, 4);                // c0+c1 (subs hold identical copies)
    float inv = rsqrtf(ssp);

    if (sub == 0) {
        float* op = out + (size_t)i * OUT_DIM + c * 8;
        float4 o0, o1;
        o0.x = r[0] * inv; o0.y = r[1] * inv; o0.z = r[2] * inv; o0.w = r[3] * inv;
        o1.x = r[4] * inv; o1.y = r[5] * inv; o1.z = r[6] * inv; o1.w = r[7] * inv;
        *(float4*)op = o0;
        *(float4*)(op + 4) = o1;
        if (c == 0) {
            float xv = di * va + bv[0];
            float sp = fmaxf(xv, 0.f) + log1pf(expf(-fabsf(xv)));   // stable softplus
            out[(size_t)N_NODES * OUT_DIM + i] = sp + 1.0f;
        }
    }
}

// ---------------- launch ----------------

extern "C" void kernel_launch(void* const* d_in, const int* in_sizes, int n_in,
                              void* d_out, int out_size, void* d_ws, size_t ws_size,
                              hipStream_t stream) {
    const float* x  = (const float*)d_in[0];
    const int*   ei = (const int*)d_in[1];
    const float* W1 = (const float*)d_in[2];
    const float* b1 = (const float*)d_in[3];
    const float* Wm = (const float*)d_in[4];
    const float* bm = (const float*)d_in[5];
    const float* Wv = (const float*)d_in[6];
    const float* bv = (const float*)d_in[7];
    float* out = (float*)d_out;

    const int* src = ei;
    const int* dst = ei + N_EDGES;

    // workspace layout; pairs region (12.8 MB) reused for hs + h
    int*   wsi     = (int*)d_ws;
    int*   csr_src = wsi;                               // E                (12.8 MB)
    int*   row_ptr = csr_src + N_EDGES;                 // N+1
    int*   row_mid = row_ptr + N_NODES + 1;             // N
    float* dinv    = (float*)(row_mid + N_NODES);       // N
    int*   hist_g  = (int*)(dinv + N_NODES);            // NHIST = 200192
    int*   sums    = hist_g + NHIST;                    // 1024 (782 used)
    size_t off     = (size_t)(sums + 1024 - wsi);
    off = (off + 3) & ~(size_t)3;                       // 16B align
    unsigned int* pairs = (unsigned int*)(wsi + off);   // E uint32 (12.8 MB)
    half_t* hs     = (half_t*)pairs;                    // N*32 fp16 (6.4 MB)  } overlay
    half_t* h      = hs + (size_t)N_NODES * H_DIM;      // N*32 fp16 (6.4 MB)  } = pairs
    half_t* hmv    = h + (size_t)N_NODES * H_DIM;       // N*16 fp16 (3.2 MB)
    float*  varr   = (float*)(hmv + (size_t)N_NODES * OUT_DIM);  // N fp32 (0.4 MB)
    half_t* h_part = (half_t*)(varr + N_NODES);         // N*32 fp16 (6.4 MB)

    const int B = 256;
    int gN  = (N_NODES + B - 1) / B;        // 391
    int gN4 = (N_NODES * 4 + B - 1) / B;    // 1563

    // --- CSR build (no per-edge global atomics) ---
    k_p1_hist<<<B1, B, 0, stream>>>(dst, hist_g);
    k_scanA<<<SUMS_N, B, 0, stream>>>(hist_g, sums);
    k_scanB<<<1, B, 0, stream>>>(sums);
    k_scanC<<<SUMS_N, B, 0, stream>>>(hist_g, sums);
    k_p3<<<B1, B, 0, stream>>>(src, dst, hist_g, pairs);
    k_p4<<<NB, 512, 0, stream>>>(pairs, hist_g, csr_src, row_ptr, row_mid, dinv);

    // --- layer 1 ---
    k_gemm1<<<gN, B, 0, stream>>>(x, W1, dinv, hs);
    k_gather1A<<<gN4, B, 0, stream>>>(row_ptr, row_mid, csr_src, hs, h_part);
    k_gather1B<<<gN4, B, 0, stream>>>(row_ptr, row_mid, csr_src, dinv, hs, h_part, b1, h);

    // --- layer 2 ---
    k_gemm2<<<gN, B, 0, stream>>>(h, Wm, Wv, dinv, hmv, varr);
    k_gather2f<<<gN4, B, 0, stream>>>(row_ptr, csr_src, dinv, hmv, varr, bm, bv, out);
}